// Round 1
// 941.117 us; speedup vs baseline: 1.0653x; 1.0653x over previous
//
#include <hip/hip_runtime.h>
#include <hip/hip_bf16.h>
#include <math.h>
#include <stdint.h>

#define N_NODES 100000
#define N_EDGES 3200000
#define D 64
#define NUM_RELS 20
#define HID_ATTR 32
#define OUT_ATTR 10
#define NKEYS (N_NODES * NUM_RELS)       // 2,000,000 sort bins (dst*20+rel)
#define SCAN2_B 7813                     // ceil(NKEYS / 256)
#define PADR 72                          // A-tile row stride in bf16 (144 B, 16B-aligned)

typedef __attribute__((ext_vector_type(8))) short bf16x8;
typedef __attribute__((ext_vector_type(4))) float f32x4;

static __device__ __forceinline__ unsigned short f2bf(float x) {
    unsigned u = __builtin_bit_cast(unsigned, x);
    unsigned r = (u + 0x7FFFu + ((u >> 16) & 1u)) >> 16;
    return (unsigned short)r;
}
static __device__ __forceinline__ float bf2f(unsigned short b) {
    return __builtin_bit_cast(float, (unsigned)b << 16);
}
static __device__ __forceinline__ float bf2f_lo(unsigned u) {
    return __builtin_bit_cast(float, u << 16);
}
static __device__ __forceinline__ float bf2f_hi(unsigned u) {
    return __builtin_bit_cast(float, u & 0xFFFF0000u);
}
// packed f32->bf16 RNE (bit-identical to f2bf above for finite inputs):
// dst[15:0]=bf16(lo), dst[31:16]=bf16(hi)
static __device__ __forceinline__ unsigned cvt_pk_bf16(float lo, float hi) {
    unsigned r;
    asm("v_cvt_pk_bf16_f32 %0, %1, %2" : "=v"(r) : "v"(lo), "v"(hi));
    return r;
}

// ---------------- CSR build: counting sort by key = dst*20 + rel ----------------

__global__ void deg_count2(const int* __restrict__ dst, const int* __restrict__ etype,
                           int* __restrict__ deg2) {
    int e = blockIdx.x * 256 + threadIdx.x;
    atomicAdd(&deg2[dst[e] * NUM_RELS + etype[e]], 1);
}

__global__ void scan2_bsum(const int* __restrict__ deg2, int* __restrict__ bsum) {
    __shared__ int s[256];
    int t = threadIdx.x, i = blockIdx.x * 256 + t;
    s[t] = (i < NKEYS) ? deg2[i] : 0;
    __syncthreads();
    for (int d2 = 128; d2 > 0; d2 >>= 1) {
        if (t < d2) s[t] += s[t + d2];
        __syncthreads();
    }
    if (t == 0) bsum[blockIdx.x] = s[0];
}

__global__ void scan2_bbase(const int* __restrict__ bsum, int* __restrict__ bbase,
                            int* __restrict__ off2) {
    __shared__ int s[1024];
    int t = threadIdx.x;
    int loc[8];
    int sum = 0;
    int b0 = t * 8;
#pragma unroll
    for (int j = 0; j < 8; ++j) {
        int b = b0 + j;
        int v = (b < SCAN2_B) ? bsum[b] : 0;
        loc[j] = sum; sum += v;
    }
    s[t] = sum;
    __syncthreads();
    for (int d2 = 1; d2 < 1024; d2 <<= 1) {
        int x = (t >= d2) ? s[t - d2] : 0;
        __syncthreads();
        s[t] += x;
        __syncthreads();
    }
    int base = (t > 0) ? s[t - 1] : 0;
#pragma unroll
    for (int j = 0; j < 8; ++j) {
        int b = b0 + j;
        if (b < SCAN2_B) bbase[b] = base + loc[j];
    }
    if (t == 0) off2[NKEYS] = N_EDGES;
}

__global__ void scan2_final(const int* __restrict__ deg2, const int* __restrict__ bbase,
                            int* __restrict__ off2, int* __restrict__ cur2) {
    __shared__ int s[256];
    int t = threadIdx.x, i = blockIdx.x * 256 + t;
    int v = (i < NKEYS) ? deg2[i] : 0;
    s[t] = v;
    __syncthreads();
    for (int d2 = 1; d2 < 256; d2 <<= 1) {
        int x = (t >= d2) ? s[t - d2] : 0;
        __syncthreads();
        s[t] += x;
        __syncthreads();
    }
    if (i < NKEYS) {
        int e = bbase[blockIdx.x] + s[t] - v;
        off2[i] = e; cur2[i] = e;
    }
}

// pack (src, rel): src < 2^17, rel < 2^5
__global__ void scatter_edges2(const int* __restrict__ src, const int* __restrict__ dst,
                               const int* __restrict__ etype, int* __restrict__ cur2,
                               int* __restrict__ edgedata) {
    int e = blockIdx.x * 256 + threadIdx.x;
    int key = dst[e] * NUM_RELS + etype[e];
    int pos = atomicAdd(&cur2[key], 1);
    edgedata[pos] = src[e] | (etype[e] << 17);
}

// ---------------- dtype conversions ----------------

__global__ void f2b_kernel(const float* __restrict__ in, unsigned short* __restrict__ out,
                           int n4) {
    int i = blockIdx.x * 256 + threadIdx.x;
    if (i >= n4) return;
    float4 v = ((const float4*)in)[i];
    ushort4 o;
    o.x = f2bf(v.x); o.y = f2bf(v.y); o.z = f2bf(v.z); o.w = f2bf(v.w);
    ((ushort4*)out)[i] = o;
}

// W[r][d][o] fp32 -> Wb[r][o][d] bf16 (B-frag layout, verified round 4)
__global__ void wconv_kernel(const float* __restrict__ W, unsigned short* __restrict__ Wb) {
    int r = blockIdx.x;
    for (int i = threadIdx.x; i < D * D; i += 256) {
        int d2 = i >> 6, o = i & 63;
        Wb[(size_t)r * (D * D) + o * D + d2] = f2bf(W[(size_t)r * (D * D) + d2 * D + o]);
    }
}

// ---------------- fused layer ----------------
// Block = 16 dst nodes, 4 waves. Each wave is split into four 16-lane groups;
// group g of wave w owns dst m = w*4+g, each lane owns 4 contiguous columns
// (uint2 = 4 bf16 per gather load, ds_write_b64 per store). One wave
// instruction now advances 4 edges (one per group) -> ~3-4x fewer wave
// VMEM/DS insts and ~2.5x fewer VALU insts per edge than the 64-lane/edge
// version. Run accumulation is branchless and numerically IDENTICAL:
//   acc = (q==qcur ? acc : 0) + x;  A[q][m][cols] = cvt_pk_bf16(acc)  (overwrite)
// v_cvt_pk_bf16_f32 is RNE = same rounding as f2bf. Groups loop to the max
// trip count of their wave (exec-masked when done). Then all 4 waves do the
// 40-MFMA transform (round-4-verified layouts). mode 1: relu'd bf16; mode 2: fp32.
__global__ __launch_bounds__(256, 3) void fused_layer(
    const unsigned short* __restrict__ xb, const unsigned short* __restrict__ Wb,
    const int* __restrict__ edgedata, const int* __restrict__ off2,
    unsigned short* __restrict__ xbout, float* __restrict__ h2out, int mode) {
    __shared__ __align__(16) unsigned short A[NUM_RELS * 16 * PADR];  // 46080 B
    int wave = threadIdx.x >> 6, lane = threadIdx.x & 63;
    int grp = lane >> 4, l4 = lane & 15;
    int m = wave * 4 + grp;            // dst index within block, 0..15
    int colb = l4 * 4;                 // column base, 0..60

    for (int i = threadIdx.x; i < NUM_RELS * 16 * PADR / 8; i += 256)
        ((int4*)A)[i] = (int4){0, 0, 0, 0};
    __syncthreads();

    int n0 = blockIdx.x * 16;
    int beg = off2[(n0 + m) * NUM_RELS];
    int end = off2[(n0 + m) * NUM_RELS + NUM_RELS];
    int cnt = end - beg;
    int nf = cnt >> 3, tl = cnt & 7;
    // wave-uniform max trip counts across the 4 groups
    int nfmax = max(nf, __shfl_xor(nf, 16));
    nfmax = max(nfmax, __shfl_xor(nfmax, 32));
    int tlmax = max(tl, __shfl_xor(tl, 16));
    tlmax = max(tlmax, __shfl_xor(tlmax, 32));

    float a0 = 0.f, a1 = 0.f, a2 = 0.f, a3 = 0.f;
    int qcur = -1;
    unsigned short* Am = A + (unsigned)m * PADR + (unsigned)colb;

    int i = beg;
    int ew[8];
    if (nf > 0) {
#pragma unroll
        for (int j = 0; j < 8; ++j) ew[j] = edgedata[i + j];
    }
    for (int g = 0; g < nfmax; ++g) {
        bool act = g < nf;
        if (act) {
            int ewc[8];
#pragma unroll
            for (int j = 0; j < 8; ++j) ewc[j] = ew[j];
            if (g + 1 < nf) {
#pragma unroll
                for (int j = 0; j < 8; ++j) ew[j] = edgedata[i + 8 + j];
            }
            uint2 xv[8];
#pragma unroll
            for (int j = 0; j < 8; ++j)
                xv[j] = *(const uint2*)(xb + (((unsigned)(ewc[j] & 0x1FFFF)) << 6)
                                        + (unsigned)colb);
#pragma unroll
            for (int j = 0; j < 8; ++j) {
                int q = ewc[j] >> 17;
                bool keep = (q == qcur);
                a0 = (keep ? a0 : 0.f) + bf2f_lo(xv[j].x);
                a1 = (keep ? a1 : 0.f) + bf2f_hi(xv[j].x);
                a2 = (keep ? a2 : 0.f) + bf2f_lo(xv[j].y);
                a3 = (keep ? a3 : 0.f) + bf2f_hi(xv[j].y);
                uint2 o;
                o.x = cvt_pk_bf16(a0, a1);
                o.y = cvt_pk_bf16(a2, a3);
                *(uint2*)(Am + (unsigned)q * (16 * PADR)) = o;
                qcur = q;
            }
            i += 8;
        }
    }
    for (int k = 0; k < tlmax; ++k) {
        if (k < tl) {
            int ewc = edgedata[i + k];
            uint2 v = *(const uint2*)(xb + (((unsigned)(ewc & 0x1FFFF)) << 6)
                                      + (unsigned)colb);
            int q = ewc >> 17;
            bool keep = (q == qcur);
            a0 = (keep ? a0 : 0.f) + bf2f_lo(v.x);
            a1 = (keep ? a1 : 0.f) + bf2f_hi(v.x);
            a2 = (keep ? a2 : 0.f) + bf2f_lo(v.y);
            a3 = (keep ? a3 : 0.f) + bf2f_hi(v.y);
            uint2 o;
            o.x = cvt_pk_bf16(a0, a1);
            o.y = cvt_pk_bf16(a2, a3);
            *(uint2*)(Am + (unsigned)q * (16 * PADR)) = o;
            qcur = q;
        }
    }
    __syncthreads();

    // all 4 waves: transform. wave w covers output columns w*16..w*16+15
    {
        int lrow = lane & 15, lhi = lane >> 4;
        f32x4 C = {0.f, 0.f, 0.f, 0.f};
        for (int q = 0; q < NUM_RELS; ++q) {
            const unsigned short* Arow = &A[(q * 16 + lrow) * PADR + lhi * 8];
            bf16x8 aa0 = *(const bf16x8*)(Arow);        // k = lhi*8 + j
            bf16x8 aa1 = *(const bf16x8*)(Arow + 32);   // k = 32 + lhi*8 + j
            const unsigned short* wrow = Wb + ((size_t)q << 12)
                                         + (size_t)(wave * 16 + lrow) * D + lhi * 8;
            bf16x8 b0 = *(const bf16x8*)(wrow);
            bf16x8 b1 = *(const bf16x8*)(wrow + 32);
            C = __builtin_amdgcn_mfma_f32_16x16x32_bf16(aa0, b0, C, 0, 0, 0);
            C = __builtin_amdgcn_mfma_f32_16x16x32_bf16(aa1, b1, C, 0, 0, 0);
        }
        // C/D: row = lhi*4 + reg (dst-local), col = wave*16 + lrow
#pragma unroll
        for (int reg = 0; reg < 4; ++reg) {
            int node = n0 + lhi * 4 + reg;
            int col = wave * 16 + lrow;
            if (mode == 1)
                xbout[(size_t)node * D + col] = f2bf(fmaxf(C[reg], 0.f));
            else
                h2out[(size_t)node * D + col] = C[reg];
        }
    }
}

// ---------------- readout ----------------

__global__ void colsum_kernel(const float* __restrict__ h2,
                              float* __restrict__ g, int n) {
    __shared__ float s[256];
    int tid = threadIdx.x;
    int col = tid & 63;
    int rowgrp = (blockIdx.x * blockDim.x + tid) >> 6;
    int nrowgrp = (gridDim.x * blockDim.x) >> 6;
    float acc = 0.0f;
    for (int row = rowgrp; row < n; row += nrowgrp)
        acc += h2[(size_t)row * D + col];
    s[tid] = acc;
    __syncthreads();
    if (tid < 64) {
        acc = s[tid] + s[tid + 64] + s[tid + 128] + s[tid + 192];
        atomicAdd(&g[col], acc);
    }
}

__global__ void mlp_kernel(const float* __restrict__ g,
                           const float* __restrict__ A1w,
                           const float* __restrict__ A1b,
                           const float* __restrict__ A2w,
                           const float* __restrict__ A2b,
                           float* __restrict__ out, float invN) {
    __shared__ float a1[HID_ATTR];
    int t = threadIdx.x;
    if (t < HID_ATTR) {
        float acc = A1b[t];
#pragma unroll
        for (int d2 = 0; d2 < D; ++d2)
            acc = fmaf(g[d2] * invN, A1w[d2 * HID_ATTR + t], acc);
        a1[t] = fmaxf(acc, 0.0f);
    }
    __syncthreads();
    if (t < OUT_ATTR) {
        float acc = A2b[t];
#pragma unroll
        for (int j = 0; j < HID_ATTR; ++j)
            acc = fmaf(a1[j], A2w[j * OUT_ATTR + t], acc);
        out[t] = 1.0f / (1.0f + expf(-acc));
    }
}

// ---------------- launch ----------------

extern "C" void kernel_launch(void* const* d_in, const int* in_sizes, int n_in,
                              void* d_out, int out_size, void* d_ws, size_t ws_size,
                              hipStream_t stream) {
    const float* h   = (const float*)d_in[0];
    const int* src   = (const int*)d_in[1];
    const int* dst   = (const int*)d_in[2];
    const int* etype = (const int*)d_in[3];
    const float* W1  = (const float*)d_in[4];
    const float* W2  = (const float*)d_in[5];
    const float* A1w = (const float*)d_in[6];
    const float* A1b = (const float*)d_in[7];
    const float* A2w = (const float*)d_in[8];
    const float* A2b = (const float*)d_in[9];

    float* out_h2 = (float*)d_out;
    float* out_a  = out_h2 + (size_t)N_NODES * D;

    // workspace layout (int offsets from d_ws; all buffers 16B-aligned)
    int* base     = (int*)d_ws;
    float* gsum   = (float*)base;                 // 64 f32
    int* deg2     = base + 64;                    // 2,000,000
    int* off2     = base + 2000064;               // 2,000,001 (pad to 2,000,064)
    int* cur2     = base + 4000128;               // 2,000,000
    int* bsum2    = base + 6000128;               // 7,813 (pad 7,872)
    int* bbase2   = base + 6008000;               // 7,872
    int* edgedata = base + 6015872;               // 3,200,000
    unsigned short* xb  = (unsigned short*)(base + 9215872);   // 6.4M u16
    unsigned short* xb2 = (unsigned short*)(base + 12415872);  // 6.4M u16
    unsigned short* w1b = (unsigned short*)(base + 15615872);  // 81,920 u16
    unsigned short* w2b = (unsigned short*)(base + 15656832);  // 81,920 u16
    // total: 15,697,792 ints = 62.8 MB

    hipMemsetAsync(deg2, 0, (size_t)NKEYS * sizeof(int), stream);
    hipMemsetAsync(gsum, 0, 64 * sizeof(float), stream);

    // CSR sorted by (dst, rel)
    deg_count2<<<N_EDGES / 256, 256, 0, stream>>>(dst, etype, deg2);
    scan2_bsum<<<SCAN2_B, 256, 0, stream>>>(deg2, bsum2);
    scan2_bbase<<<1, 1024, 0, stream>>>(bsum2, bbase2, off2);
    scan2_final<<<SCAN2_B, 256, 0, stream>>>(deg2, bbase2, off2, cur2);
    scatter_edges2<<<N_EDGES / 256, 256, 0, stream>>>(src, dst, etype, cur2, edgedata);

    // conversions
    wconv_kernel<<<NUM_RELS, 256, 0, stream>>>(W1, w1b);
    wconv_kernel<<<NUM_RELS, 256, 0, stream>>>(W2, w2b);
    f2b_kernel<<<(N_NODES * D / 4 + 255) / 256, 256, 0, stream>>>(h, xb, N_NODES * D / 4);

    // two fused RGCN layers
    fused_layer<<<N_NODES / 16, 256, 0, stream>>>(xb, w1b, edgedata, off2,
                                                  xb2, nullptr, 1);
    fused_layer<<<N_NODES / 16, 256, 0, stream>>>(xb2, w2b, edgedata, off2,
                                                  nullptr, out_h2, 2);

    // readout
    colsum_kernel<<<512, 256, 0, stream>>>(out_h2, gsum, N_NODES);
    mlp_kernel<<<1, 64, 0, stream>>>(gsum, A1w, A1b, A2w, A2b,
                                     out_a, 1.0f / (float)N_NODES);
}

// Round 2
// 665.992 us; speedup vs baseline: 1.5053x; 1.4131x over previous
//
#include <hip/hip_runtime.h>
#include <hip/hip_bf16.h>
#include <math.h>
#include <stdint.h>

#define N_NODES 100000
#define N_EDGES 3200000
#define D 64
#define NUM_RELS 20
#define HID_ATTR 32
#define OUT_ATTR 10
#define PADR 72                          // A-tile row stride in bf16 (144 B, 16B-aligned)

// two-level MSD counting sort
#define BUCKET_DSTS 256                  // dsts per coarse bucket (dst >> 8)
#define NB 391                           // ceil(100000 / 256)
#define PA_THREADS 512
#define PA_EPT 16                        // edges per thread
#define PA_CHUNK (PA_THREADS * PA_EPT)   // 8192
#define PA_GRID 391                      // ceil(3.2M / 8192)
#define PB_BINS (BUCKET_DSTS * NUM_RELS) // 5120 fine bins per bucket

typedef __attribute__((ext_vector_type(8))) short bf16x8;
typedef __attribute__((ext_vector_type(4))) float f32x4;

static __device__ __forceinline__ unsigned short f2bf(float x) {
    unsigned u = __builtin_bit_cast(unsigned, x);
    unsigned r = (u + 0x7FFFu + ((u >> 16) & 1u)) >> 16;
    return (unsigned short)r;
}
static __device__ __forceinline__ float bf2f(unsigned short b) {
    return __builtin_bit_cast(float, (unsigned)b << 16);
}
static __device__ __forceinline__ float bf2f_lo(unsigned u) {
    return __builtin_bit_cast(float, u << 16);
}
static __device__ __forceinline__ float bf2f_hi(unsigned u) {
    return __builtin_bit_cast(float, u & 0xFFFF0000u);
}
// packed f32->bf16 RNE (bit-identical to f2bf above for finite inputs)
static __device__ __forceinline__ unsigned cvt_pk_bf16(float lo, float hi) {
    unsigned r;
    asm("v_cvt_pk_bf16_f32 %0, %1, %2" : "=v"(r) : "v"(lo), "v"(hi));
    return r;
}

// ---------------- CSR build: 2-level MSD counting sort ----------------
// level 1 key: dst >> 8 (391 buckets); level 2 key: (dst&255)*20 + rel.
// tmp payload u32: dstLow[29:22] | src[21:5] | rel[4:0]
// final edgedata:  src | rel << 17  (same as before)

__global__ void hist_bucket_kernel(const int* __restrict__ dst, int* __restrict__ hist) {
    __shared__ int h[NB];
    for (int i = threadIdx.x; i < NB; i += PA_THREADS) h[i] = 0;
    __syncthreads();
    int base = blockIdx.x * PA_CHUNK;
#pragma unroll
    for (int k = 0; k < PA_EPT; ++k) {
        int e = base + k * PA_THREADS + threadIdx.x;
        if (e < N_EDGES) atomicAdd(&h[dst[e] >> 8], 1);
    }
    __syncthreads();
    for (int i = threadIdx.x; i < NB; i += PA_THREADS)
        if (h[i]) atomicAdd(&hist[i], h[i]);
}

__global__ void scan_bucket_kernel(const int* __restrict__ hist, int* __restrict__ bbase,
                                   int* __restrict__ bcur, int* __restrict__ off_node) {
    __shared__ int s[512];
    int t = threadIdx.x;
    int v = (t < NB) ? hist[t] : 0;
    s[t] = v;
    __syncthreads();
    for (int d2 = 1; d2 < 512; d2 <<= 1) {
        int x = (t >= d2) ? s[t - d2] : 0;
        __syncthreads();
        s[t] += x;
        __syncthreads();
    }
    if (t < NB) {
        int b = s[t] - v;
        bbase[t] = b;
        bcur[t] = b;
    }
    if (t == 0) {
        bbase[NB] = N_EDGES;
        off_node[N_NODES] = N_EDGES;
    }
}

__global__ __launch_bounds__(PA_THREADS) void passA_kernel(
    const int* __restrict__ src, const int* __restrict__ dst,
    const int* __restrict__ etype, int* __restrict__ bcur,
    unsigned* __restrict__ tmp) {
    __shared__ int h[NB];   // block histogram
    __shared__ int gb[NB];  // global segment base for this block
    __shared__ int c[NB];   // running within-segment count
    for (int i = threadIdx.x; i < NB; i += PA_THREADS) h[i] = 0;
    __syncthreads();
    int base = blockIdx.x * PA_CHUNK;
    int d[PA_EPT];
#pragma unroll
    for (int k = 0; k < PA_EPT; ++k) {
        int e = base + k * PA_THREADS + threadIdx.x;
        d[k] = (e < N_EDGES) ? dst[e] : -1;
        if (d[k] >= 0) atomicAdd(&h[d[k] >> 8], 1);
    }
    __syncthreads();
    for (int i = threadIdx.x; i < NB; i += PA_THREADS) {
        int n = h[i];
        gb[i] = n ? atomicAdd(&bcur[i], n) : 0;
        c[i] = 0;
    }
    __syncthreads();
#pragma unroll
    for (int k = 0; k < PA_EPT; ++k) {
        int e = base + k * PA_THREADS + threadIdx.x;
        if (d[k] >= 0) {
            int b = d[k] >> 8;
            int sv = src[e], r = etype[e];
            int pos = gb[b] + atomicAdd(&c[b], 1);
            tmp[pos] = ((unsigned)(d[k] & 255) << 22) | ((unsigned)sv << 5) | (unsigned)r;
        }
    }
}

__global__ __launch_bounds__(512) void passB_kernel(
    const unsigned* __restrict__ tmp, const int* __restrict__ bbase,
    int* __restrict__ edgedata, int* __restrict__ off_node) {
    __shared__ int binpos[PB_BINS];  // 20 KB: counts, then global positions
    __shared__ int ssum[512];
    int t = threadIdx.x;
    int b = blockIdx.x;
    int beg = bbase[b], end = bbase[b + 1];
    for (int i = t; i < PB_BINS; i += 512) binpos[i] = 0;
    __syncthreads();
    for (int i = beg + t; i < end; i += 512) {
        unsigned v = tmp[i];
        int key = (int)(v >> 22) * NUM_RELS + (int)(v & 31u);
        atomicAdd(&binpos[key], 1);
    }
    __syncthreads();
    // exclusive scan of 5120 bins; thread t owns bins [t*10, t*10+10)
    int loc[10];
    int sum = 0;
#pragma unroll
    for (int j = 0; j < 10; ++j) {
        loc[j] = sum;
        sum += binpos[t * 10 + j];
    }
    ssum[t] = sum;
    __syncthreads();
    for (int d2 = 1; d2 < 512; d2 <<= 1) {
        int x = (t >= d2) ? ssum[t - d2] : 0;
        __syncthreads();
        ssum[t] += x;
        __syncthreads();
    }
    int tbase = beg + ((t > 0) ? ssum[t - 1] : 0);
#pragma unroll
    for (int j = 0; j < 10; ++j) binpos[t * 10 + j] = tbase + loc[j];
    __syncthreads();
    // per-node CSR offsets: node (b*256+dl) starts at bin dl*20
    for (int dl = t; dl < BUCKET_DSTS; dl += 512)
        off_node[b * BUCKET_DSTS + dl] = binpos[dl * NUM_RELS];
    __syncthreads();
    for (int i = beg + t; i < end; i += 512) {
        unsigned v = tmp[i];
        int key = (int)(v >> 22) * NUM_RELS + (int)(v & 31u);
        int pos = atomicAdd(&binpos[key], 1);
        edgedata[pos] = (int)(((v >> 5) & 0x1FFFFu) | ((v & 31u) << 17));
    }
}

// ---------------- dtype conversions ----------------

__global__ void f2b_kernel(const float* __restrict__ in, unsigned short* __restrict__ out,
                           int n4) {
    int i = blockIdx.x * 256 + threadIdx.x;
    if (i >= n4) return;
    float4 v = ((const float4*)in)[i];
    ushort4 o;
    o.x = f2bf(v.x); o.y = f2bf(v.y); o.z = f2bf(v.z); o.w = f2bf(v.w);
    ((ushort4*)out)[i] = o;
}

// W[r][d][o] fp32 -> Wb[r][o][d] bf16 (B-frag layout, verified round 4)
__global__ void wconv_kernel(const float* __restrict__ W, unsigned short* __restrict__ Wb) {
    int r = blockIdx.x;
    for (int i = threadIdx.x; i < D * D; i += 256) {
        int d2 = i >> 6, o = i & 63;
        Wb[(size_t)r * (D * D) + o * D + d2] = f2bf(W[(size_t)r * (D * D) + d2 * D + o]);
    }
}

// ---------------- fused layer ----------------
// Block = 16 dst nodes, 4 waves. Each wave is split into four 16-lane groups;
// group g of wave w owns dst m = w*4+g, each lane owns 4 contiguous columns
// (uint2 = 4 bf16 per gather load, ds_write_b64 per store). Run accumulation
// is branchless: acc = (q==qcur ? acc : 0) + x; A[q][m][cols] = bf16(acc).
// Then all 4 waves do the 40-MFMA transform (round-4-verified layouts).
// mode 1: relu'd bf16 out; mode 2: fp32 out.
__global__ __launch_bounds__(256, 3) void fused_layer(
    const unsigned short* __restrict__ xb, const unsigned short* __restrict__ Wb,
    const int* __restrict__ edgedata, const int* __restrict__ off_node,
    unsigned short* __restrict__ xbout, float* __restrict__ h2out, int mode) {
    __shared__ __align__(16) unsigned short A[NUM_RELS * 16 * PADR];  // 46080 B
    int wave = threadIdx.x >> 6, lane = threadIdx.x & 63;
    int grp = lane >> 4, l4 = lane & 15;
    int m = wave * 4 + grp;            // dst index within block, 0..15
    int colb = l4 * 4;                 // column base, 0..60

    for (int i = threadIdx.x; i < NUM_RELS * 16 * PADR / 8; i += 256)
        ((int4*)A)[i] = (int4){0, 0, 0, 0};
    __syncthreads();

    int n0 = blockIdx.x * 16;
    int beg = off_node[n0 + m];
    int end = off_node[n0 + m + 1];
    int cnt = end - beg;
    int nf = cnt >> 3, tl = cnt & 7;
    // wave-uniform max trip counts across the 4 groups
    int nfmax = max(nf, __shfl_xor(nf, 16));
    nfmax = max(nfmax, __shfl_xor(nfmax, 32));
    int tlmax = max(tl, __shfl_xor(tl, 16));
    tlmax = max(tlmax, __shfl_xor(tlmax, 32));

    float a0 = 0.f, a1 = 0.f, a2 = 0.f, a3 = 0.f;
    int qcur = -1;
    unsigned short* Am = A + (unsigned)m * PADR + (unsigned)colb;

    int i = beg;
    int ew[8];
    if (nf > 0) {
#pragma unroll
        for (int j = 0; j < 8; ++j) ew[j] = edgedata[i + j];
    }
    for (int g = 0; g < nfmax; ++g) {
        bool act = g < nf;
        if (act) {
            int ewc[8];
#pragma unroll
            for (int j = 0; j < 8; ++j) ewc[j] = ew[j];
            if (g + 1 < nf) {
#pragma unroll
                for (int j = 0; j < 8; ++j) ew[j] = edgedata[i + 8 + j];
            }
            uint2 xv[8];
#pragma unroll
            for (int j = 0; j < 8; ++j)
                xv[j] = *(const uint2*)(xb + (((unsigned)(ewc[j] & 0x1FFFF)) << 6)
                                        + (unsigned)colb);
#pragma unroll
            for (int j = 0; j < 8; ++j) {
                int q = ewc[j] >> 17;
                bool keep = (q == qcur);
                a0 = (keep ? a0 : 0.f) + bf2f_lo(xv[j].x);
                a1 = (keep ? a1 : 0.f) + bf2f_hi(xv[j].x);
                a2 = (keep ? a2 : 0.f) + bf2f_lo(xv[j].y);
                a3 = (keep ? a3 : 0.f) + bf2f_hi(xv[j].y);
                uint2 o;
                o.x = cvt_pk_bf16(a0, a1);
                o.y = cvt_pk_bf16(a2, a3);
                *(uint2*)(Am + (unsigned)q * (16 * PADR)) = o;
                qcur = q;
            }
            i += 8;
        }
    }
    for (int k = 0; k < tlmax; ++k) {
        if (k < tl) {
            int ewc = edgedata[i + k];
            uint2 v = *(const uint2*)(xb + (((unsigned)(ewc & 0x1FFFF)) << 6)
                                      + (unsigned)colb);
            int q = ewc >> 17;
            bool keep = (q == qcur);
            a0 = (keep ? a0 : 0.f) + bf2f_lo(v.x);
            a1 = (keep ? a1 : 0.f) + bf2f_hi(v.x);
            a2 = (keep ? a2 : 0.f) + bf2f_lo(v.y);
            a3 = (keep ? a3 : 0.f) + bf2f_hi(v.y);
            uint2 o;
            o.x = cvt_pk_bf16(a0, a1);
            o.y = cvt_pk_bf16(a2, a3);
            *(uint2*)(Am + (unsigned)q * (16 * PADR)) = o;
            qcur = q;
        }
    }
    __syncthreads();

    // all 4 waves: transform. wave w covers output columns w*16..w*16+15
    {
        int lrow = lane & 15, lhi = lane >> 4;
        f32x4 C = {0.f, 0.f, 0.f, 0.f};
        for (int q = 0; q < NUM_RELS; ++q) {
            const unsigned short* Arow = &A[(q * 16 + lrow) * PADR + lhi * 8];
            bf16x8 aa0 = *(const bf16x8*)(Arow);        // k = lhi*8 + j
            bf16x8 aa1 = *(const bf16x8*)(Arow + 32);   // k = 32 + lhi*8 + j
            const unsigned short* wrow = Wb + ((size_t)q << 12)
                                         + (size_t)(wave * 16 + lrow) * D + lhi * 8;
            bf16x8 b0 = *(const bf16x8*)(wrow);
            bf16x8 b1 = *(const bf16x8*)(wrow + 32);
            C = __builtin_amdgcn_mfma_f32_16x16x32_bf16(aa0, b0, C, 0, 0, 0);
            C = __builtin_amdgcn_mfma_f32_16x16x32_bf16(aa1, b1, C, 0, 0, 0);
        }
        // C/D: row = lhi*4 + reg (dst-local), col = wave*16 + lrow
#pragma unroll
        for (int reg = 0; reg < 4; ++reg) {
            int node = n0 + lhi * 4 + reg;
            int col = wave * 16 + lrow;
            if (mode == 1)
                xbout[(size_t)node * D + col] = f2bf(fmaxf(C[reg], 0.f));
            else
                h2out[(size_t)node * D + col] = C[reg];
        }
    }
}

// ---------------- readout ----------------

__global__ void colsum_kernel(const float* __restrict__ h2,
                              float* __restrict__ g, int n) {
    __shared__ float s[256];
    int tid = threadIdx.x;
    int col = tid & 63;
    int rowgrp = (blockIdx.x * blockDim.x + tid) >> 6;
    int nrowgrp = (gridDim.x * blockDim.x) >> 6;
    float acc = 0.0f;
    for (int row = rowgrp; row < n; row += nrowgrp)
        acc += h2[(size_t)row * D + col];
    s[tid] = acc;
    __syncthreads();
    if (tid < 64) {
        acc = s[tid] + s[tid + 64] + s[tid + 128] + s[tid + 192];
        atomicAdd(&g[col], acc);
    }
}

__global__ void mlp_kernel(const float* __restrict__ g,
                           const float* __restrict__ A1w,
                           const float* __restrict__ A1b,
                           const float* __restrict__ A2w,
                           const float* __restrict__ A2b,
                           float* __restrict__ out, float invN) {
    __shared__ float a1[HID_ATTR];
    int t = threadIdx.x;
    if (t < HID_ATTR) {
        float acc = A1b[t];
#pragma unroll
        for (int d2 = 0; d2 < D; ++d2)
            acc = fmaf(g[d2] * invN, A1w[d2 * HID_ATTR + t], acc);
        a1[t] = fmaxf(acc, 0.0f);
    }
    __syncthreads();
    if (t < OUT_ATTR) {
        float acc = A2b[t];
#pragma unroll
        for (int j = 0; j < HID_ATTR; ++j)
            acc = fmaf(a1[j], A2w[j * OUT_ATTR + t], acc);
        out[t] = 1.0f / (1.0f + expf(-acc));
    }
}

// ---------------- launch ----------------

extern "C" void kernel_launch(void* const* d_in, const int* in_sizes, int n_in,
                              void* d_out, int out_size, void* d_ws, size_t ws_size,
                              hipStream_t stream) {
    const float* h   = (const float*)d_in[0];
    const int* src   = (const int*)d_in[1];
    const int* dst   = (const int*)d_in[2];
    const int* etype = (const int*)d_in[3];
    const float* W1  = (const float*)d_in[4];
    const float* W2  = (const float*)d_in[5];
    const float* A1w = (const float*)d_in[6];
    const float* A1b = (const float*)d_in[7];
    const float* A2w = (const float*)d_in[8];
    const float* A2b = (const float*)d_in[9];

    float* out_h2 = (float*)d_out;
    float* out_a  = out_h2 + (size_t)N_NODES * D;

    // workspace layout (int offsets from d_ws; all buffers 16B-aligned)
    int* base       = (int*)d_ws;
    float* gsum     = (float*)base;               // 64 f32
    int* hist_b     = base + 64;                  // 392 (NB padded)
    int* bbase      = base + 456;                 // 392 (NB+1)
    int* bcur       = base + 848;                 // 392
    int* off_node   = base + 1240;                // 100,352 (covers NB*256 + 1)
    unsigned* tmp   = (unsigned*)(base + 101592); // 3,200,000
    int* edgedata   = base + 3301592;             // 3,200,000
    unsigned short* xb  = (unsigned short*)(base + 6501592);   // 6.4M u16
    unsigned short* xb2 = (unsigned short*)(base + 9701592);   // 6.4M u16
    unsigned short* w1b = (unsigned short*)(base + 12901592);  // 81,920 u16
    unsigned short* w2b = (unsigned short*)(base + 12942552);  // 81,920 u16
    // total: 12,983,512 ints = 51.9 MB

    hipMemsetAsync(hist_b, 0, NB * sizeof(int), stream);
    hipMemsetAsync(gsum, 0, 64 * sizeof(float), stream);

    // CSR sorted by (dst, rel): 2-level MSD counting sort
    hist_bucket_kernel<<<PA_GRID, PA_THREADS, 0, stream>>>(dst, hist_b);
    scan_bucket_kernel<<<1, 512, 0, stream>>>(hist_b, bbase, bcur, off_node);
    passA_kernel<<<PA_GRID, PA_THREADS, 0, stream>>>(src, dst, etype, bcur, tmp);
    passB_kernel<<<NB, 512, 0, stream>>>(tmp, bbase, edgedata, off_node);

    // conversions
    wconv_kernel<<<NUM_RELS, 256, 0, stream>>>(W1, w1b);
    wconv_kernel<<<NUM_RELS, 256, 0, stream>>>(W2, w2b);
    f2b_kernel<<<(N_NODES * D / 4 + 255) / 256, 256, 0, stream>>>(h, xb, N_NODES * D / 4);

    // two fused RGCN layers
    fused_layer<<<N_NODES / 16, 256, 0, stream>>>(xb, w1b, edgedata, off_node,
                                                  xb2, nullptr, 1);
    fused_layer<<<N_NODES / 16, 256, 0, stream>>>(xb2, w2b, edgedata, off_node,
                                                  nullptr, out_h2, 2);

    // readout
    colsum_kernel<<<512, 256, 0, stream>>>(out_h2, gsum, N_NODES);
    mlp_kernel<<<1, 64, 0, stream>>>(gsum, A1w, A1b, A2w, A2b,
                                     out_a, 1.0f / (float)N_NODES);
}

// Round 3
// 643.033 us; speedup vs baseline: 1.5591x; 1.0357x over previous
//
#include <hip/hip_runtime.h>
#include <hip/hip_bf16.h>
#include <math.h>
#include <stdint.h>

#define N_NODES 100000
#define N_EDGES 3200000
#define D 64
#define NUM_RELS 20
#define HID_ATTR 32
#define OUT_ATTR 10
#define PADR 72                          // A-tile row stride in bf16 (144 B, 16B-aligned)

// two-level MSD counting sort
#define BUCKET_DSTS 256                  // dsts per coarse bucket (dst >> 8)
#define NB 391                           // ceil(100000 / 256)
#define PA_THREADS 512
#define PA_EPT 16                        // edges per thread
#define PA_CHUNK (PA_THREADS * PA_EPT)   // 8192
#define PA_GRID 391                      // ceil(3.2M / 8192)
#define PB_BINS (BUCKET_DSTS * NUM_RELS) // 5120 fine bins per bucket
#define REL_HALF 10                      // rel split for dual-walk fused layer

typedef __attribute__((ext_vector_type(8))) short bf16x8;
typedef __attribute__((ext_vector_type(4))) float f32x4;

static __device__ __forceinline__ unsigned short f2bf(float x) {
    unsigned u = __builtin_bit_cast(unsigned, x);
    unsigned r = (u + 0x7FFFu + ((u >> 16) & 1u)) >> 16;
    return (unsigned short)r;
}
static __device__ __forceinline__ float bf2f(unsigned short b) {
    return __builtin_bit_cast(float, (unsigned)b << 16);
}
static __device__ __forceinline__ float bf2f_lo(unsigned u) {
    return __builtin_bit_cast(float, u << 16);
}
static __device__ __forceinline__ float bf2f_hi(unsigned u) {
    return __builtin_bit_cast(float, u & 0xFFFF0000u);
}
// packed f32->bf16 RNE (bit-identical to f2bf above for finite inputs)
static __device__ __forceinline__ unsigned cvt_pk_bf16(float lo, float hi) {
    unsigned r;
    asm("v_cvt_pk_bf16_f32 %0, %1, %2" : "=v"(r) : "v"(lo), "v"(hi));
    return r;
}

// ---------------- CSR build: 2-level MSD counting sort ----------------
// level 1 key: dst >> 8 (391 buckets); level 2 key: (dst&255)*20 + rel.
// tmp payload u32: dstLow[29:22] | src[21:5] | rel[4:0]
// final edgedata:  src | rel << 17

__global__ void hist_bucket_kernel(const int* __restrict__ dst, int* __restrict__ hist) {
    __shared__ int h[NB];
    for (int i = threadIdx.x; i < NB; i += PA_THREADS) h[i] = 0;
    __syncthreads();
    int base = blockIdx.x * PA_CHUNK;
#pragma unroll
    for (int k = 0; k < PA_EPT; ++k) {
        int e = base + k * PA_THREADS + threadIdx.x;
        if (e < N_EDGES) atomicAdd(&h[dst[e] >> 8], 1);
    }
    __syncthreads();
    for (int i = threadIdx.x; i < NB; i += PA_THREADS)
        if (h[i]) atomicAdd(&hist[i], h[i]);
}

__global__ void scan_bucket_kernel(const int* __restrict__ hist, int* __restrict__ bbase,
                                   int* __restrict__ bcur, int* __restrict__ off_node) {
    __shared__ int s[512];
    int t = threadIdx.x;
    int v = (t < NB) ? hist[t] : 0;
    s[t] = v;
    __syncthreads();
    for (int d2 = 1; d2 < 512; d2 <<= 1) {
        int x = (t >= d2) ? s[t - d2] : 0;
        __syncthreads();
        s[t] += x;
        __syncthreads();
    }
    if (t < NB) {
        int b = s[t] - v;
        bbase[t] = b;
        bcur[t] = b;
    }
    if (t == 0) {
        bbase[NB] = N_EDGES;
        off_node[N_NODES] = N_EDGES;
    }
}

__global__ __launch_bounds__(PA_THREADS) void passA_kernel(
    const int* __restrict__ src, const int* __restrict__ dst,
    const int* __restrict__ etype, int* __restrict__ bcur,
    unsigned* __restrict__ tmp) {
    __shared__ int h[NB];   // block histogram
    __shared__ int gb[NB];  // global segment base for this block
    __shared__ int c[NB];   // running within-segment count
    for (int i = threadIdx.x; i < NB; i += PA_THREADS) h[i] = 0;
    __syncthreads();
    int base = blockIdx.x * PA_CHUNK;
    int d[PA_EPT];
#pragma unroll
    for (int k = 0; k < PA_EPT; ++k) {
        int e = base + k * PA_THREADS + threadIdx.x;
        d[k] = (e < N_EDGES) ? dst[e] : -1;
        if (d[k] >= 0) atomicAdd(&h[d[k] >> 8], 1);
    }
    __syncthreads();
    for (int i = threadIdx.x; i < NB; i += PA_THREADS) {
        int n = h[i];
        gb[i] = n ? atomicAdd(&bcur[i], n) : 0;
        c[i] = 0;
    }
    __syncthreads();
#pragma unroll
    for (int k = 0; k < PA_EPT; ++k) {
        int e = base + k * PA_THREADS + threadIdx.x;
        if (d[k] >= 0) {
            int b = d[k] >> 8;
            int sv = src[e], r = etype[e];
            int pos = gb[b] + atomicAdd(&c[b], 1);
            tmp[pos] = ((unsigned)(d[k] & 255) << 22) | ((unsigned)sv << 5) | (unsigned)r;
        }
    }
}

__global__ __launch_bounds__(512) void passB_kernel(
    const unsigned* __restrict__ tmp, const int* __restrict__ bbase,
    int* __restrict__ edgedata, int* __restrict__ off_node,
    int* __restrict__ off_half) {
    __shared__ int binpos[PB_BINS];  // 20 KB: counts, then global positions
    __shared__ int ssum[512];
    int t = threadIdx.x;
    int b = blockIdx.x;
    int beg = bbase[b], end = bbase[b + 1];
    for (int i = t; i < PB_BINS; i += 512) binpos[i] = 0;
    __syncthreads();
    for (int i = beg + t; i < end; i += 512) {
        unsigned v = tmp[i];
        int key = (int)(v >> 22) * NUM_RELS + (int)(v & 31u);
        atomicAdd(&binpos[key], 1);
    }
    __syncthreads();
    // exclusive scan of 5120 bins; thread t owns bins [t*10, t*10+10)
    int loc[10];
    int sum = 0;
#pragma unroll
    for (int j = 0; j < 10; ++j) {
        loc[j] = sum;
        sum += binpos[t * 10 + j];
    }
    ssum[t] = sum;
    __syncthreads();
    for (int d2 = 1; d2 < 512; d2 <<= 1) {
        int x = (t >= d2) ? ssum[t - d2] : 0;
        __syncthreads();
        ssum[t] += x;
        __syncthreads();
    }
    int tbase = beg + ((t > 0) ? ssum[t - 1] : 0);
#pragma unroll
    for (int j = 0; j < 10; ++j) binpos[t * 10 + j] = tbase + loc[j];
    __syncthreads();
    // per-node CSR offsets: node (b*256+dl) starts at bin dl*20;
    // rel-half split (first edge with rel >= REL_HALF) at bin dl*20+REL_HALF
    for (int dl = t; dl < BUCKET_DSTS; dl += 512) {
        off_node[b * BUCKET_DSTS + dl] = binpos[dl * NUM_RELS];
        off_half[b * BUCKET_DSTS + dl] = binpos[dl * NUM_RELS + REL_HALF];
    }
    __syncthreads();
    for (int i = beg + t; i < end; i += 512) {
        unsigned v = tmp[i];
        int key = (int)(v >> 22) * NUM_RELS + (int)(v & 31u);
        int pos = atomicAdd(&binpos[key], 1);
        edgedata[pos] = (int)(((v >> 5) & 0x1FFFFu) | ((v & 31u) << 17));
    }
}

// ---------------- dtype conversions ----------------

__global__ void f2b_kernel(const float* __restrict__ in, unsigned short* __restrict__ out,
                           int n4) {
    int i = blockIdx.x * 256 + threadIdx.x;
    if (i >= n4) return;
    float4 v = ((const float4*)in)[i];
    ushort4 o;
    o.x = f2bf(v.x); o.y = f2bf(v.y); o.z = f2bf(v.z); o.w = f2bf(v.w);
    ((ushort4*)out)[i] = o;
}

// W[r][d][o] fp32 -> Wb[r][o][d] bf16 (B-frag layout, verified round 4)
__global__ void wconv_kernel(const float* __restrict__ W, unsigned short* __restrict__ Wb) {
    int r = blockIdx.x;
    for (int i = threadIdx.x; i < D * D; i += 256) {
        int d2 = i >> 6, o = i & 63;
        Wb[(size_t)r * (D * D) + o * D + d2] = f2bf(W[(size_t)r * (D * D) + d2 * D + o]);
    }
}

// ---------------- fused layer ----------------
// Block = 16 dst nodes, 8 waves (512 thr). Each wave has four 16-lane groups;
// group index gidx = wave*4+grp in [0,32): dst m = gidx&15, rel-half
// h = gidx>>4 (h=0: rels 0..9 via [off_node, off_half), h=1: rels 10..19 via
// [off_half, off_node+1)). Runs never cross the half boundary and the halves
// write disjoint A rows -> accumulation bit-identical to the single-walk
// version. LDS (46 KB) allows 3 blocks/CU -> 24 waves/CU (was 12): 2x the
// in-flight gathers for the latency-bound random x-row reads.
// Per lane: 4 contiguous columns (uint2 gather, ds_write_b64), branchless run
// accumulation: acc = (q==qcur ? acc : 0) + x; A[q][m][cols] = bf16(acc).
// Waves 0-3 then do the 40-MFMA transform (round-4-verified layouts).
// mode 1: relu'd bf16 out; mode 2: fp32 out.
__global__ __launch_bounds__(512, 6) void fused_layer(
    const unsigned short* __restrict__ xb, const unsigned short* __restrict__ Wb,
    const int* __restrict__ edgedata, const int* __restrict__ off_node,
    const int* __restrict__ off_half,
    unsigned short* __restrict__ xbout, float* __restrict__ h2out, int mode) {
    __shared__ __align__(16) unsigned short A[NUM_RELS * 16 * PADR];  // 46080 B
    int wave = threadIdx.x >> 6, lane = threadIdx.x & 63;
    int grp = lane >> 4, l4 = lane & 15;
    int gidx = wave * 4 + grp;         // 0..31
    int m = gidx & 15;                 // dst index within block
    int h = gidx >> 4;                 // rel half
    int colb = l4 * 4;                 // column base, 0..60

    for (int i = threadIdx.x; i < NUM_RELS * 16 * PADR / 8; i += 512)
        ((int4*)A)[i] = (int4){0, 0, 0, 0};
    __syncthreads();

    int n0 = blockIdx.x * 16;
    int node = n0 + m;
    int beg = h ? off_half[node] : off_node[node];
    int end = h ? off_node[node + 1] : off_half[node];
    int cnt = end - beg;
    int nf = cnt >> 3, tl = cnt & 7;
    // wave-uniform max trip counts across the 4 groups
    int nfmax = max(nf, __shfl_xor(nf, 16));
    nfmax = max(nfmax, __shfl_xor(nfmax, 32));
    int tlmax = max(tl, __shfl_xor(tl, 16));
    tlmax = max(tlmax, __shfl_xor(tlmax, 32));

    float a0 = 0.f, a1 = 0.f, a2 = 0.f, a3 = 0.f;
    int qcur = -1;
    unsigned short* Am = A + (unsigned)m * PADR + (unsigned)colb;

    int i = beg;
    int ew[8];
    if (nf > 0) {
#pragma unroll
        for (int j = 0; j < 8; ++j) ew[j] = edgedata[i + j];
    }
    for (int g = 0; g < nfmax; ++g) {
        bool act = g < nf;
        if (act) {
            int ewc[8];
#pragma unroll
            for (int j = 0; j < 8; ++j) ewc[j] = ew[j];
            if (g + 1 < nf) {
#pragma unroll
                for (int j = 0; j < 8; ++j) ew[j] = edgedata[i + 8 + j];
            }
            uint2 xv[8];
#pragma unroll
            for (int j = 0; j < 8; ++j)
                xv[j] = *(const uint2*)(xb + (((unsigned)(ewc[j] & 0x1FFFF)) << 6)
                                        + (unsigned)colb);
#pragma unroll
            for (int j = 0; j < 8; ++j) {
                int q = ewc[j] >> 17;
                bool keep = (q == qcur);
                a0 = (keep ? a0 : 0.f) + bf2f_lo(xv[j].x);
                a1 = (keep ? a1 : 0.f) + bf2f_hi(xv[j].x);
                a2 = (keep ? a2 : 0.f) + bf2f_lo(xv[j].y);
                a3 = (keep ? a3 : 0.f) + bf2f_hi(xv[j].y);
                uint2 o;
                o.x = cvt_pk_bf16(a0, a1);
                o.y = cvt_pk_bf16(a2, a3);
                *(uint2*)(Am + (unsigned)q * (16 * PADR)) = o;
                qcur = q;
            }
            i += 8;
        }
    }
    for (int k = 0; k < tlmax; ++k) {
        if (k < tl) {
            int ewc = edgedata[i + k];
            uint2 v = *(const uint2*)(xb + (((unsigned)(ewc & 0x1FFFF)) << 6)
                                      + (unsigned)colb);
            int q = ewc >> 17;
            bool keep = (q == qcur);
            a0 = (keep ? a0 : 0.f) + bf2f_lo(v.x);
            a1 = (keep ? a1 : 0.f) + bf2f_hi(v.x);
            a2 = (keep ? a2 : 0.f) + bf2f_lo(v.y);
            a3 = (keep ? a3 : 0.f) + bf2f_hi(v.y);
            uint2 o;
            o.x = cvt_pk_bf16(a0, a1);
            o.y = cvt_pk_bf16(a2, a3);
            *(uint2*)(Am + (unsigned)q * (16 * PADR)) = o;
            qcur = q;
        }
    }
    __syncthreads();

    // waves 0-3: transform. wave w covers output columns w*16..w*16+15
    if (wave < 4) {
        int lrow = lane & 15, lhi = lane >> 4;
        f32x4 C = {0.f, 0.f, 0.f, 0.f};
        for (int q = 0; q < NUM_RELS; ++q) {
            const unsigned short* Arow = &A[(q * 16 + lrow) * PADR + lhi * 8];
            bf16x8 aa0 = *(const bf16x8*)(Arow);        // k = lhi*8 + j
            bf16x8 aa1 = *(const bf16x8*)(Arow + 32);   // k = 32 + lhi*8 + j
            const unsigned short* wrow = Wb + ((size_t)q << 12)
                                         + (size_t)(wave * 16 + lrow) * D + lhi * 8;
            bf16x8 b0 = *(const bf16x8*)(wrow);
            bf16x8 b1 = *(const bf16x8*)(wrow + 32);
            C = __builtin_amdgcn_mfma_f32_16x16x32_bf16(aa0, b0, C, 0, 0, 0);
            C = __builtin_amdgcn_mfma_f32_16x16x32_bf16(aa1, b1, C, 0, 0, 0);
        }
        // C/D: row = lhi*4 + reg (dst-local), col = wave*16 + lrow
#pragma unroll
        for (int reg = 0; reg < 4; ++reg) {
            int onode = n0 + lhi * 4 + reg;
            int col = wave * 16 + lrow;
            if (mode == 1)
                xbout[(size_t)onode * D + col] = f2bf(fmaxf(C[reg], 0.f));
            else
                h2out[(size_t)onode * D + col] = C[reg];
        }
    }
}

// ---------------- readout ----------------

__global__ void colsum_kernel(const float* __restrict__ h2,
                              float* __restrict__ g, int n) {
    __shared__ float s[256];
    int tid = threadIdx.x;
    int col = tid & 63;
    int rowgrp = (blockIdx.x * blockDim.x + tid) >> 6;
    int nrowgrp = (gridDim.x * blockDim.x) >> 6;
    float acc = 0.0f;
    for (int row = rowgrp; row < n; row += nrowgrp)
        acc += h2[(size_t)row * D + col];
    s[tid] = acc;
    __syncthreads();
    if (tid < 64) {
        acc = s[tid] + s[tid + 64] + s[tid + 128] + s[tid + 192];
        atomicAdd(&g[col], acc);
    }
}

__global__ void mlp_kernel(const float* __restrict__ g,
                           const float* __restrict__ A1w,
                           const float* __restrict__ A1b,
                           const float* __restrict__ A2w,
                           const float* __restrict__ A2b,
                           float* __restrict__ out, float invN) {
    __shared__ float a1[HID_ATTR];
    int t = threadIdx.x;
    if (t < HID_ATTR) {
        float acc = A1b[t];
#pragma unroll
        for (int d2 = 0; d2 < D; ++d2)
            acc = fmaf(g[d2] * invN, A1w[d2 * HID_ATTR + t], acc);
        a1[t] = fmaxf(acc, 0.0f);
    }
    __syncthreads();
    if (t < OUT_ATTR) {
        float acc = A2b[t];
#pragma unroll
        for (int j = 0; j < HID_ATTR; ++j)
            acc = fmaf(a1[j], A2w[j * OUT_ATTR + t], acc);
        out[t] = 1.0f / (1.0f + expf(-acc));
    }
}

// ---------------- launch ----------------

extern "C" void kernel_launch(void* const* d_in, const int* in_sizes, int n_in,
                              void* d_out, int out_size, void* d_ws, size_t ws_size,
                              hipStream_t stream) {
    const float* h   = (const float*)d_in[0];
    const int* src   = (const int*)d_in[1];
    const int* dst   = (const int*)d_in[2];
    const int* etype = (const int*)d_in[3];
    const float* W1  = (const float*)d_in[4];
    const float* W2  = (const float*)d_in[5];
    const float* A1w = (const float*)d_in[6];
    const float* A1b = (const float*)d_in[7];
    const float* A2w = (const float*)d_in[8];
    const float* A2b = (const float*)d_in[9];

    float* out_h2 = (float*)d_out;
    float* out_a  = out_h2 + (size_t)N_NODES * D;

    // workspace layout (int offsets from d_ws; all buffers 16B-aligned)
    int* base       = (int*)d_ws;
    float* gsum     = (float*)base;               // 64 f32
    int* hist_b     = base + 64;                  // 392 (NB padded)
    int* bbase      = base + 456;                 // 392 (NB+1)
    int* bcur       = base + 848;                 // 392
    int* off_node   = base + 1240;                // 100,352 (covers NB*256 + 1)
    int* off_half   = base + 101592;              // 100,352
    unsigned* tmp   = (unsigned*)(base + 201944); // 3,200,000
    int* edgedata   = base + 3401944;             // 3,200,000
    unsigned short* xb  = (unsigned short*)(base + 6601944);   // 6.4M u16
    unsigned short* xb2 = (unsigned short*)(base + 9801944);   // 6.4M u16
    unsigned short* w1b = (unsigned short*)(base + 13001944);  // 81,920 u16
    unsigned short* w2b = (unsigned short*)(base + 13042904);  // 81,920 u16
    // total: 13,083,864 ints = 52.3 MB

    hipMemsetAsync(hist_b, 0, NB * sizeof(int), stream);
    hipMemsetAsync(gsum, 0, 64 * sizeof(float), stream);

    // CSR sorted by (dst, rel): 2-level MSD counting sort
    hist_bucket_kernel<<<PA_GRID, PA_THREADS, 0, stream>>>(dst, hist_b);
    scan_bucket_kernel<<<1, 512, 0, stream>>>(hist_b, bbase, bcur, off_node);
    passA_kernel<<<PA_GRID, PA_THREADS, 0, stream>>>(src, dst, etype, bcur, tmp);
    passB_kernel<<<NB, 512, 0, stream>>>(tmp, bbase, edgedata, off_node, off_half);

    // conversions
    wconv_kernel<<<NUM_RELS, 256, 0, stream>>>(W1, w1b);
    wconv_kernel<<<NUM_RELS, 256, 0, stream>>>(W2, w2b);
    f2b_kernel<<<(N_NODES * D / 4 + 255) / 256, 256, 0, stream>>>(h, xb, N_NODES * D / 4);

    // two fused RGCN layers
    fused_layer<<<N_NODES / 16, 512, 0, stream>>>(xb, w1b, edgedata, off_node,
                                                  off_half, xb2, nullptr, 1);
    fused_layer<<<N_NODES / 16, 512, 0, stream>>>(xb2, w2b, edgedata, off_node,
                                                  off_half, nullptr, out_h2, 2);

    // readout
    colsum_kernel<<<512, 256, 0, stream>>>(out_h2, gsum, N_NODES);
    mlp_kernel<<<1, 64, 0, stream>>>(gsum, A1w, A1b, A2w, A2b,
                                     out_a, 1.0f / (float)N_NODES);
}

// Round 4
// 601.808 us; speedup vs baseline: 1.6659x; 1.0685x over previous
//
#include <hip/hip_runtime.h>
#include <hip/hip_bf16.h>
#include <math.h>
#include <stdint.h>

#define N_NODES 100000
#define N_EDGES 3200000
#define D 64
#define NUM_RELS 20
#define HID_ATTR 32
#define OUT_ATTR 10
#define PADR 72                          // A-tile row stride in bf16 (144 B, 16B-aligned)

// two-level MSD counting sort
#define BUCKET_DSTS 256                  // dsts per coarse bucket (dst >> 8)
#define NB 391                           // ceil(100000 / 256)
#define PA_THREADS 512
#define PA_EPT 16                        // edges per thread
#define PA_CHUNK (PA_THREADS * PA_EPT)   // 8192
#define PA_GRID 391                      // ceil(3.2M / 8192)
#define PB_BINS (BUCKET_DSTS * NUM_RELS) // 5120 fine bins per bucket
#define REL_HALF 10                      // rel split for dual-walk fused layer

typedef __attribute__((ext_vector_type(8))) short bf16x8;
typedef __attribute__((ext_vector_type(4))) float f32x4;

static __device__ __forceinline__ unsigned short f2bf(float x) {
    unsigned u = __builtin_bit_cast(unsigned, x);
    unsigned r = (u + 0x7FFFu + ((u >> 16) & 1u)) >> 16;
    return (unsigned short)r;
}
static __device__ __forceinline__ float bf2f(unsigned short b) {
    return __builtin_bit_cast(float, (unsigned)b << 16);
}
static __device__ __forceinline__ float bf2f_lo(unsigned u) {
    return __builtin_bit_cast(float, u << 16);
}
static __device__ __forceinline__ float bf2f_hi(unsigned u) {
    return __builtin_bit_cast(float, u & 0xFFFF0000u);
}
// packed f32->bf16 RNE (bit-identical to f2bf above for finite inputs)
static __device__ __forceinline__ unsigned cvt_pk_bf16(float lo, float hi) {
    unsigned r;
    asm("v_cvt_pk_bf16_f32 %0, %1, %2" : "=v"(r) : "v"(lo), "v"(hi));
    return r;
}

// ---------------- CSR build: 2-level MSD counting sort ----------------
// level 1 key: dst >> 8 (391 buckets); level 2 key: (dst&255)*20 + rel.
// tmp payload u32: dstLow[29:22] | src[21:5] | rel[4:0]
// final edgedata:  src | rel << 17

__global__ void hist_bucket_kernel(const int* __restrict__ dst, int* __restrict__ hist) {
    __shared__ int h[NB];
    for (int i = threadIdx.x; i < NB; i += PA_THREADS) h[i] = 0;
    __syncthreads();
    int base = blockIdx.x * PA_CHUNK;
#pragma unroll
    for (int k = 0; k < PA_EPT; ++k) {
        int e = base + k * PA_THREADS + threadIdx.x;
        if (e < N_EDGES) atomicAdd(&h[dst[e] >> 8], 1);
    }
    __syncthreads();
    for (int i = threadIdx.x; i < NB; i += PA_THREADS)
        if (h[i]) atomicAdd(&hist[i], h[i]);
}

__global__ void scan_bucket_kernel(const int* __restrict__ hist, int* __restrict__ bbase,
                                   int* __restrict__ bcur, int* __restrict__ off_node) {
    __shared__ int s[512];
    int t = threadIdx.x;
    int v = (t < NB) ? hist[t] : 0;
    s[t] = v;
    __syncthreads();
    for (int d2 = 1; d2 < 512; d2 <<= 1) {
        int x = (t >= d2) ? s[t - d2] : 0;
        __syncthreads();
        s[t] += x;
        __syncthreads();
    }
    if (t < NB) {
        int b = s[t] - v;
        bbase[t] = b;
        bcur[t] = b;
    }
    if (t == 0) {
        bbase[NB] = N_EDGES;
        off_node[N_NODES] = N_EDGES;
    }
}

__global__ __launch_bounds__(PA_THREADS) void passA_kernel(
    const int* __restrict__ src, const int* __restrict__ dst,
    const int* __restrict__ etype, int* __restrict__ bcur,
    unsigned* __restrict__ tmp) {
    __shared__ int h[NB];   // block histogram
    __shared__ int gb[NB];  // global segment base for this block
    __shared__ int c[NB];   // running within-segment count
    for (int i = threadIdx.x; i < NB; i += PA_THREADS) h[i] = 0;
    __syncthreads();
    int base = blockIdx.x * PA_CHUNK;
    int d[PA_EPT];
#pragma unroll
    for (int k = 0; k < PA_EPT; ++k) {
        int e = base + k * PA_THREADS + threadIdx.x;
        d[k] = (e < N_EDGES) ? dst[e] : -1;
        if (d[k] >= 0) atomicAdd(&h[d[k] >> 8], 1);
    }
    __syncthreads();
    for (int i = threadIdx.x; i < NB; i += PA_THREADS) {
        int n = h[i];
        gb[i] = n ? atomicAdd(&bcur[i], n) : 0;
        c[i] = 0;
    }
    __syncthreads();
#pragma unroll
    for (int k = 0; k < PA_EPT; ++k) {
        int e = base + k * PA_THREADS + threadIdx.x;
        if (d[k] >= 0) {
            int b = d[k] >> 8;
            int sv = src[e], r = etype[e];
            int pos = gb[b] + atomicAdd(&c[b], 1);
            tmp[pos] = ((unsigned)(d[k] & 255) << 22) | ((unsigned)sv << 5) | (unsigned)r;
        }
    }
}

__global__ __launch_bounds__(512) void passB_kernel(
    const unsigned* __restrict__ tmp, const int* __restrict__ bbase,
    int* __restrict__ edgedata, int* __restrict__ off_node,
    int* __restrict__ off_half) {
    __shared__ int binpos[PB_BINS];  // 20 KB: counts, then global positions
    __shared__ int ssum[512];
    int t = threadIdx.x;
    int b = blockIdx.x;
    int beg = bbase[b], end = bbase[b + 1];
    for (int i = t; i < PB_BINS; i += 512) binpos[i] = 0;
    __syncthreads();
    for (int i = beg + t; i < end; i += 512) {
        unsigned v = tmp[i];
        int key = (int)(v >> 22) * NUM_RELS + (int)(v & 31u);
        atomicAdd(&binpos[key], 1);
    }
    __syncthreads();
    // exclusive scan of 5120 bins; thread t owns bins [t*10, t*10+10)
    int loc[10];
    int sum = 0;
#pragma unroll
    for (int j = 0; j < 10; ++j) {
        loc[j] = sum;
        sum += binpos[t * 10 + j];
    }
    ssum[t] = sum;
    __syncthreads();
    for (int d2 = 1; d2 < 512; d2 <<= 1) {
        int x = (t >= d2) ? ssum[t - d2] : 0;
        __syncthreads();
        ssum[t] += x;
        __syncthreads();
    }
    int tbase = beg + ((t > 0) ? ssum[t - 1] : 0);
#pragma unroll
    for (int j = 0; j < 10; ++j) binpos[t * 10 + j] = tbase + loc[j];
    __syncthreads();
    // per-node CSR offsets: node (b*256+dl) starts at bin dl*20;
    // rel-half split (first edge with rel >= REL_HALF) at bin dl*20+REL_HALF
    for (int dl = t; dl < BUCKET_DSTS; dl += 512) {
        off_node[b * BUCKET_DSTS + dl] = binpos[dl * NUM_RELS];
        off_half[b * BUCKET_DSTS + dl] = binpos[dl * NUM_RELS + REL_HALF];
    }
    __syncthreads();
    for (int i = beg + t; i < end; i += 512) {
        unsigned v = tmp[i];
        int key = (int)(v >> 22) * NUM_RELS + (int)(v & 31u);
        int pos = atomicAdd(&binpos[key], 1);
        edgedata[pos] = (int)(((v >> 5) & 0x1FFFFu) | ((v & 31u) << 17));
    }
}

// ---------------- dtype conversions ----------------

__global__ void f2b_kernel(const float* __restrict__ in, unsigned short* __restrict__ out,
                           int n4) {
    int i = blockIdx.x * 256 + threadIdx.x;
    if (i >= n4) return;
    float4 v = ((const float4*)in)[i];
    ushort4 o;
    o.x = f2bf(v.x); o.y = f2bf(v.y); o.z = f2bf(v.z); o.w = f2bf(v.w);
    ((ushort4*)out)[i] = o;
}

// W[r][d][o] fp32 -> Wb[r][o][d] bf16 (B-frag layout, verified round 4)
__global__ void wconv_kernel(const float* __restrict__ W, unsigned short* __restrict__ Wb) {
    int r = blockIdx.x;
    for (int i = threadIdx.x; i < D * D; i += 256) {
        int d2 = i >> 6, o = i & 63;
        Wb[(size_t)r * (D * D) + o * D + d2] = f2bf(W[(size_t)r * (D * D) + d2 * D + o]);
    }
}

// ---------------- fused layer ----------------
// Block = 16 dst nodes, 8 waves (512 thr). Each wave has four 16-lane groups;
// gidx = wave*4+grp in [0,32): dst m = gidx&15, rel-half h = gidx>>4.
// Gather is software-pipelined with double-buffered ew/xv: each phase issues
// edge-words for batch g+2 and row-gathers for batch g+1, then processes
// batch g (whose gathers got ~1 full phase of latency cover). The tail is
// merged into the last batch: load indices clamp to end-1 (valid addresses),
// padded x-values forced to 0 -> acc unchanged, A[qcur] rewritten with the
// same bytes => numerics bit-identical to the unpipelined version.
// Branchless run accumulation: acc = (q==qcur ? acc : 0) + x;
// A[q][m][cols] = bf16(acc) (overwrite). Waves 0-3 then do the 40-MFMA
// transform (round-4-verified layouts). mode 1: relu'd bf16; mode 2: fp32.
__global__ __launch_bounds__(512, 6) void fused_layer(
    const unsigned short* __restrict__ xb, const unsigned short* __restrict__ Wb,
    const int* __restrict__ edgedata, const int* __restrict__ off_node,
    const int* __restrict__ off_half,
    unsigned short* __restrict__ xbout, float* __restrict__ h2out, int mode) {
    __shared__ __align__(16) unsigned short A[NUM_RELS * 16 * PADR];  // 46080 B
    int wave = threadIdx.x >> 6, lane = threadIdx.x & 63;
    int grp = lane >> 4, l4 = lane & 15;
    int gidx = wave * 4 + grp;         // 0..31
    int m = gidx & 15;                 // dst index within block
    int h = gidx >> 4;                 // rel half
    int colb = l4 * 4;                 // column base, 0..60

    for (int i = threadIdx.x; i < NUM_RELS * 16 * PADR / 8; i += 512)
        ((int4*)A)[i] = (int4){0, 0, 0, 0};
    __syncthreads();

    int n0 = blockIdx.x * 16;
    int node = n0 + m;
    int beg = h ? off_half[node] : off_node[node];
    int end = h ? off_node[node + 1] : off_half[node];
    int cnt = end - beg;
    int nb = (cnt + 7) >> 3;           // number of (padded) batches
    int nbmax = max(nb, __shfl_xor(nb, 16));
    nbmax = max(nbmax, __shfl_xor(nbmax, 32));
    int endm1 = end - 1;

    float a0 = 0.f, a1 = 0.f, a2 = 0.f, a3 = 0.f;
    int qcur = -1;
    unsigned short* Am = A + (unsigned)m * PADR + (unsigned)colb;

    auto rowload = [&](int ewv) -> uint2 {
        return *(const uint2*)(xb + (((unsigned)(ewv & 0x1FFFF)) << 6)
                               + (unsigned)colb);
    };
    auto proc = [&](int (&ewc)[8], uint2 (&xv)[8], int valid) {
#pragma unroll
        for (int j = 0; j < 8; ++j) {
            int q = ewc[j] >> 17;
            bool real = j < valid;
            unsigned mx = real ? xv[j].x : 0u;
            unsigned my = real ? xv[j].y : 0u;
            bool keep = (q == qcur);
            a0 = (keep ? a0 : 0.f) + bf2f_lo(mx);
            a1 = (keep ? a1 : 0.f) + bf2f_hi(mx);
            a2 = (keep ? a2 : 0.f) + bf2f_lo(my);
            a3 = (keep ? a3 : 0.f) + bf2f_hi(my);
            uint2 o;
            o.x = cvt_pk_bf16(a0, a1);
            o.y = cvt_pk_bf16(a2, a3);
            *(uint2*)(Am + (unsigned)q * (16 * PADR)) = o;
            qcur = q;
        }
    };

    int ewA[8], ewB[8];
    uint2 xvA[8], xvB[8];
    if (nb > 0) {
#pragma unroll
        for (int j = 0; j < 8; ++j) ewA[j] = edgedata[min(beg + j, endm1)];
    }
    if (nb > 1) {
#pragma unroll
        for (int j = 0; j < 8; ++j) ewB[j] = edgedata[min(beg + 8 + j, endm1)];
    }
    if (nb > 0) {
#pragma unroll
        for (int j = 0; j < 8; ++j) xvA[j] = rowload(ewA[j]);
    }

    for (int g = 0; g < nbmax;) {
        {   // even phase: current = A buffers, next = B
            bool act = g < nb;
            if (act) {
                int ewc[8];
#pragma unroll
                for (int j = 0; j < 8; ++j) ewc[j] = ewA[j];
                int nbase = beg + (g + 2) * 8;
                if (g + 2 < nb) {
#pragma unroll
                    for (int j = 0; j < 8; ++j)
                        ewA[j] = edgedata[min(nbase + j, endm1)];
                }
                if (g + 1 < nb) {
#pragma unroll
                    for (int j = 0; j < 8; ++j) xvB[j] = rowload(ewB[j]);
                }
                proc(ewc, xvA, cnt - g * 8);
            }
        }
        ++g;
        if (g >= nbmax) break;
        {   // odd phase: current = B buffers, next = A
            bool act = g < nb;
            if (act) {
                int ewc[8];
#pragma unroll
                for (int j = 0; j < 8; ++j) ewc[j] = ewB[j];
                int nbase = beg + (g + 2) * 8;
                if (g + 2 < nb) {
#pragma unroll
                    for (int j = 0; j < 8; ++j)
                        ewB[j] = edgedata[min(nbase + j, endm1)];
                }
                if (g + 1 < nb) {
#pragma unroll
                    for (int j = 0; j < 8; ++j) xvA[j] = rowload(ewA[j]);
                }
                proc(ewc, xvB, cnt - g * 8);
            }
        }
        ++g;
    }
    __syncthreads();

    // waves 0-3: transform. wave w covers output columns w*16..w*16+15
    if (wave < 4) {
        int lrow = lane & 15, lhi = lane >> 4;
        f32x4 C = {0.f, 0.f, 0.f, 0.f};
        for (int q = 0; q < NUM_RELS; ++q) {
            const unsigned short* Arow = &A[(q * 16 + lrow) * PADR + lhi * 8];
            bf16x8 aa0 = *(const bf16x8*)(Arow);        // k = lhi*8 + j
            bf16x8 aa1 = *(const bf16x8*)(Arow + 32);   // k = 32 + lhi*8 + j
            const unsigned short* wrow = Wb + ((size_t)q << 12)
                                         + (size_t)(wave * 16 + lrow) * D + lhi * 8;
            bf16x8 b0 = *(const bf16x8*)(wrow);
            bf16x8 b1 = *(const bf16x8*)(wrow + 32);
            C = __builtin_amdgcn_mfma_f32_16x16x32_bf16(aa0, b0, C, 0, 0, 0);
            C = __builtin_amdgcn_mfma_f32_16x16x32_bf16(aa1, b1, C, 0, 0, 0);
        }
        // C/D: row = lhi*4 + reg (dst-local), col = wave*16 + lrow
#pragma unroll
        for (int reg = 0; reg < 4; ++reg) {
            int onode = n0 + lhi * 4 + reg;
            int col = wave * 16 + lrow;
            if (mode == 1)
                xbout[(size_t)onode * D + col] = f2bf(fmaxf(C[reg], 0.f));
            else
                h2out[(size_t)onode * D + col] = C[reg];
        }
    }
}

// ---------------- readout ----------------

__global__ void colsum_kernel(const float* __restrict__ h2,
                              float* __restrict__ g, int n) {
    __shared__ float s[256];
    int tid = threadIdx.x;
    int col = tid & 63;
    int rowgrp = (blockIdx.x * blockDim.x + tid) >> 6;
    int nrowgrp = (gridDim.x * blockDim.x) >> 6;
    float acc = 0.0f;
    for (int row = rowgrp; row < n; row += nrowgrp)
        acc += h2[(size_t)row * D + col];
    s[tid] = acc;
    __syncthreads();
    if (tid < 64) {
        acc = s[tid] + s[tid + 64] + s[tid + 128] + s[tid + 192];
        atomicAdd(&g[col], acc);
    }
}

__global__ void mlp_kernel(const float* __restrict__ g,
                           const float* __restrict__ A1w,
                           const float* __restrict__ A1b,
                           const float* __restrict__ A2w,
                           const float* __restrict__ A2b,
                           float* __restrict__ out, float invN) {
    __shared__ float a1[HID_ATTR];
    int t = threadIdx.x;
    if (t < HID_ATTR) {
        float acc = A1b[t];
#pragma unroll
        for (int d2 = 0; d2 < D; ++d2)
            acc = fmaf(g[d2] * invN, A1w[d2 * HID_ATTR + t], acc);
        a1[t] = fmaxf(acc, 0.0f);
    }
    __syncthreads();
    if (t < OUT_ATTR) {
        float acc = A2b[t];
#pragma unroll
        for (int j = 0; j < HID_ATTR; ++j)
            acc = fmaf(a1[j], A2w[j * OUT_ATTR + t], acc);
        out[t] = 1.0f / (1.0f + expf(-acc));
    }
}

// ---------------- launch ----------------

extern "C" void kernel_launch(void* const* d_in, const int* in_sizes, int n_in,
                              void* d_out, int out_size, void* d_ws, size_t ws_size,
                              hipStream_t stream) {
    const float* h   = (const float*)d_in[0];
    const int* src   = (const int*)d_in[1];
    const int* dst   = (const int*)d_in[2];
    const int* etype = (const int*)d_in[3];
    const float* W1  = (const float*)d_in[4];
    const float* W2  = (const float*)d_in[5];
    const float* A1w = (const float*)d_in[6];
    const float* A1b = (const float*)d_in[7];
    const float* A2w = (const float*)d_in[8];
    const float* A2b = (const float*)d_in[9];

    float* out_h2 = (float*)d_out;
    float* out_a  = out_h2 + (size_t)N_NODES * D;

    // workspace layout (int offsets from d_ws; all buffers 16B-aligned)
    int* base       = (int*)d_ws;
    float* gsum     = (float*)base;               // 64 f32
    int* hist_b     = base + 64;                  // 392 (NB padded)
    int* bbase      = base + 456;                 // 392 (NB+1)
    int* bcur       = base + 848;                 // 392
    int* off_node   = base + 1240;                // 100,352 (covers NB*256 + 1)
    int* off_half   = base + 101592;              // 100,352
    unsigned* tmp   = (unsigned*)(base + 201944); // 3,200,000
    int* edgedata   = base + 3401944;             // 3,200,000
    unsigned short* xb  = (unsigned short*)(base + 6601944);   // 6.4M u16
    unsigned short* xb2 = (unsigned short*)(base + 9801944);   // 6.4M u16
    unsigned short* w1b = (unsigned short*)(base + 13001944);  // 81,920 u16
    unsigned short* w2b = (unsigned short*)(base + 13042904);  // 81,920 u16
    // total: 13,083,864 ints = 52.3 MB

    hipMemsetAsync(hist_b, 0, NB * sizeof(int), stream);
    hipMemsetAsync(gsum, 0, 64 * sizeof(float), stream);

    // CSR sorted by (dst, rel): 2-level MSD counting sort
    hist_bucket_kernel<<<PA_GRID, PA_THREADS, 0, stream>>>(dst, hist_b);
    scan_bucket_kernel<<<1, 512, 0, stream>>>(hist_b, bbase, bcur, off_node);
    passA_kernel<<<PA_GRID, PA_THREADS, 0, stream>>>(src, dst, etype, bcur, tmp);
    passB_kernel<<<NB, 512, 0, stream>>>(tmp, bbase, edgedata, off_node, off_half);

    // conversions
    wconv_kernel<<<NUM_RELS, 256, 0, stream>>>(W1, w1b);
    wconv_kernel<<<NUM_RELS, 256, 0, stream>>>(W2, w2b);
    f2b_kernel<<<(N_NODES * D / 4 + 255) / 256, 256, 0, stream>>>(h, xb, N_NODES * D / 4);

    // two fused RGCN layers
    fused_layer<<<N_NODES / 16, 512, 0, stream>>>(xb, w1b, edgedata, off_node,
                                                  off_half, xb2, nullptr, 1);
    fused_layer<<<N_NODES / 16, 512, 0, stream>>>(xb2, w2b, edgedata, off_node,
                                                  off_half, nullptr, out_h2, 2);

    // readout
    colsum_kernel<<<512, 256, 0, stream>>>(out_h2, gsum, N_NODES);
    mlp_kernel<<<1, 64, 0, stream>>>(gsum, A1w, A1b, A2w, A2b,
                                     out_a, 1.0f / (float)N_NODES);
}

// Round 5
// 576.020 us; speedup vs baseline: 1.7404x; 1.0448x over previous
//
#include <hip/hip_runtime.h>
#include <hip/hip_bf16.h>
#include <math.h>
#include <stdint.h>

#define N_NODES 100000
#define N_EDGES 3200000
#define D 64
#define NUM_RELS 20
#define HID_ATTR 32
#define OUT_ATTR 10
#define PADR 72                          // A-tile row stride in bf16 (144 B)
#define NFB (N_NODES / 16)               // 6250 fused blocks (16 nodes each)

// two-level MSD counting sort
#define BUCKET_DSTS 256                  // dsts per coarse bucket (dst >> 8)
#define NB 391                           // ceil(100000 / 256)
#define PA_THREADS 512
#define PA_EPT 16                        // edges per thread
#define PA_CHUNK (PA_THREADS * PA_EPT)   // 8192
#define PA_GRID 391                      // ceil(3.2M / 8192)
#define PB_BINS (BUCKET_DSTS * NUM_RELS) // 5120 fine bins per bucket

typedef __attribute__((ext_vector_type(8))) short bf16x8;
typedef __attribute__((ext_vector_type(4))) float f32x4;

static __device__ __forceinline__ unsigned short f2bf(float x) {
    unsigned u = __builtin_bit_cast(unsigned, x);
    unsigned r = (u + 0x7FFFu + ((u >> 16) & 1u)) >> 16;
    return (unsigned short)r;
}
static __device__ __forceinline__ float bf2f(unsigned short b) {
    return __builtin_bit_cast(float, (unsigned)b << 16);
}
static __device__ __forceinline__ float bf2f_lo(unsigned u) {
    return __builtin_bit_cast(float, u << 16);
}
static __device__ __forceinline__ float bf2f_hi(unsigned u) {
    return __builtin_bit_cast(float, u & 0xFFFF0000u);
}
// packed f32->bf16 RNE (bit-identical to f2bf above for finite inputs)
static __device__ __forceinline__ unsigned cvt_pk_bf16(float lo, float hi) {
    unsigned r;
    asm("v_cvt_pk_bf16_f32 %0, %1, %2" : "=v"(r) : "v"(lo), "v"(hi));
    return r;
}

// ---------------- CSR build: 2-level MSD counting sort + balanced schedule --
// level 1 key: dst >> 8 (391 buckets); level 2 key: (dst&255)*20 + rel.
// tmp payload u32: dstLow[29:22] | src[21:5] | rel[4:0]
// passB additionally: per 16-node fused-block, split each node into 4
// rel-quarter walks (64 walks), sort lengths desc (bitonic), fold-pair rank k
// with rank 63-k onto 32 group slots (balanced), lay edges out in schedule
// order, emit sched_off[fb*32+g]. Final edgedata payload:
//   src[16:0] | rowoff[31:17]   where rowoff = rel*(16*PADR) + (dstLow&15)*PADR
// (rowoff <= 22968 < 2^15). Runs (same (dst,rel)) stay contiguous & whole.

__global__ void hist_bucket_kernel(const int* __restrict__ dst, int* __restrict__ hist) {
    __shared__ int h[NB];
    for (int i = threadIdx.x; i < NB; i += PA_THREADS) h[i] = 0;
    __syncthreads();
    int base = blockIdx.x * PA_CHUNK;
#pragma unroll
    for (int k = 0; k < PA_EPT; ++k) {
        int e = base + k * PA_THREADS + threadIdx.x;
        if (e < N_EDGES) atomicAdd(&h[dst[e] >> 8], 1);
    }
    __syncthreads();
    for (int i = threadIdx.x; i < NB; i += PA_THREADS)
        if (h[i]) atomicAdd(&hist[i], h[i]);
}

__global__ void scan_bucket_kernel(const int* __restrict__ hist, int* __restrict__ bbase,
                                   int* __restrict__ bcur, int* __restrict__ sched_off) {
    __shared__ int s[512];
    int t = threadIdx.x;
    int v = (t < NB) ? hist[t] : 0;
    s[t] = v;
    __syncthreads();
    for (int d2 = 1; d2 < 512; d2 <<= 1) {
        int x = (t >= d2) ? s[t - d2] : 0;
        __syncthreads();
        s[t] += x;
        __syncthreads();
    }
    if (t < NB) {
        int b = s[t] - v;
        bbase[t] = b;
        bcur[t] = b;
    }
    if (t == 0) {
        bbase[NB] = N_EDGES;
        sched_off[NFB * 32] = N_EDGES;   // global sentinel
    }
}

__global__ __launch_bounds__(PA_THREADS) void passA_kernel(
    const int* __restrict__ src, const int* __restrict__ dst,
    const int* __restrict__ etype, int* __restrict__ bcur,
    unsigned* __restrict__ tmp) {
    __shared__ int h[NB];   // block histogram
    __shared__ int gb[NB];  // global segment base for this block
    __shared__ int c[NB];   // running within-segment count
    for (int i = threadIdx.x; i < NB; i += PA_THREADS) h[i] = 0;
    __syncthreads();
    int base = blockIdx.x * PA_CHUNK;
    int d[PA_EPT];
#pragma unroll
    for (int k = 0; k < PA_EPT; ++k) {
        int e = base + k * PA_THREADS + threadIdx.x;
        d[k] = (e < N_EDGES) ? dst[e] : -1;
        if (d[k] >= 0) atomicAdd(&h[d[k] >> 8], 1);
    }
    __syncthreads();
    for (int i = threadIdx.x; i < NB; i += PA_THREADS) {
        int n = h[i];
        gb[i] = n ? atomicAdd(&bcur[i], n) : 0;
        c[i] = 0;
    }
    __syncthreads();
#pragma unroll
    for (int k = 0; k < PA_EPT; ++k) {
        int e = base + k * PA_THREADS + threadIdx.x;
        if (d[k] >= 0) {
            int b = d[k] >> 8;
            int sv = src[e], r = etype[e];
            int pos = gb[b] + atomicAdd(&c[b], 1);
            tmp[pos] = ((unsigned)(d[k] & 255) << 22) | ((unsigned)sv << 5) | (unsigned)r;
        }
    }
}

__global__ __launch_bounds__(512) void passB_kernel(
    const unsigned* __restrict__ tmp, const int* __restrict__ bbase,
    unsigned* __restrict__ edgedata, int* __restrict__ sched_off) {
    __shared__ int binpos[PB_BINS];   // 20 KB: counts -> scheduled positions
    __shared__ int blen[PB_BINS];     // 20 KB: bin lengths (saved counts)
    __shared__ unsigned sk[16 * 64];  // 4 KB: per-fb sort keys (len<<8|wloc)
    __shared__ int swo[16 * 64];      // 4 KB: per-walk scheduled offset in fb
    __shared__ int gs[512];           // 2 KB: per-fb group-total scan
    __shared__ int ssum[512];         // 2 KB: bin scan partials
    __shared__ int fbb[16];           // fb base positions
    int t = threadIdx.x;
    int b = blockIdx.x;
    int beg = bbase[b], end = bbase[b + 1];
    for (int i = t; i < PB_BINS; i += 512) binpos[i] = 0;
    __syncthreads();
    for (int i = beg + t; i < end; i += 512) {
        unsigned v = tmp[i];
        int key = (int)(v >> 22) * NUM_RELS + (int)(v & 31u);
        atomicAdd(&binpos[key], 1);
    }
    __syncthreads();
    // save lengths before scan
    for (int i = t; i < PB_BINS; i += 512) blen[i] = binpos[i];
    __syncthreads();
    // exclusive scan of 5120 bins (sorted-order bases); thread t owns 10 bins
    int loc[10];
    int sum = 0;
#pragma unroll
    for (int j = 0; j < 10; ++j) {
        loc[j] = sum;
        sum += binpos[t * 10 + j];
    }
    ssum[t] = sum;
    __syncthreads();
    for (int d2 = 1; d2 < 512; d2 <<= 1) {
        int x = (t >= d2) ? ssum[t - d2] : 0;
        __syncthreads();
        ssum[t] += x;
        __syncthreads();
    }
    int tbase = beg + ((t > 0) ? ssum[t - 1] : 0);
#pragma unroll
    for (int j = 0; j < 10; ++j) binpos[t * 10 + j] = tbase + loc[j];
    __syncthreads();
    // fb base = sorted base of its first bin (fb regions are contiguous and
    // unchanged by intra-fb permutation)
    if (t < 16) fbb[t] = binpos[t * 320];
    __syncthreads();
    // walk lengths: walk = (node_local nl, quarter qt), wloc = nl*4+qt
    for (int w = t; w < 1024; w += 512) {
        int fb = w >> 6, wloc = w & 63;
        int nl = wloc >> 2, qt = wloc & 3;
        int b0 = (fb * 16 + nl) * NUM_RELS + qt * 5;
        int len = blen[b0] + blen[b0 + 1] + blen[b0 + 2] + blen[b0 + 3] + blen[b0 + 4];
        sk[fb * 64 + wloc] = ((unsigned)len << 8) | (unsigned)wloc;
    }
    // bitonic sort desc, 64 elements per fb, 32 comparators per fb (=512 thr)
    {
        int fb = t >> 5, k = t & 31;
        unsigned* s = &sk[fb * 64];
        for (int size = 2; size <= 64; size <<= 1) {
            for (int stride = size >> 1; stride > 0; stride >>= 1) {
                __syncthreads();
                int i1 = ((k & ~(stride - 1)) << 1) | (k & (stride - 1));
                int i2 = i1 | stride;
                unsigned x = s[i1], y = s[i2];
                bool descb = (i1 & size) == 0;
                if (descb ? (x < y) : (x > y)) { s[i1] = y; s[i2] = x; }
            }
        }
    }
    __syncthreads();
    // fold-pair rank k with rank 63-k onto group slot k; scan group totals
    {
        int fb = t >> 5, k = t & 31;
        unsigned kA = sk[fb * 64 + k], kB = sk[fb * 64 + 63 - k];
        int lenA = (int)(kA >> 8), widA = (int)(kA & 63u);
        int lenB = (int)(kB >> 8), widB = (int)(kB & 63u);
        int tot = lenA + lenB;
        gs[t] = tot;
        __syncthreads();
        for (int d2 = 1; d2 < 32; d2 <<= 1) {
            int x = (k >= d2) ? gs[t - d2] : 0;
            __syncthreads();
            gs[t] += x;
            __syncthreads();
        }
        int gbase = gs[t] - tot;   // exclusive within fb
        swo[fb * 64 + widA] = gbase;
        swo[fb * 64 + widB] = gbase + lenA;
        int gfb = b * 16 + fb;
        if (gfb < NFB) sched_off[gfb * 32 + k] = fbb[fb] + gbase;
    }
    __syncthreads();
    // rewrite binpos to scheduled positions
    for (int i = t; i < PB_BINS; i += 512) {
        int node = i / 20, rel = i - node * 20;
        int fb = node >> 4, nl = node & 15;
        int qt = rel / 5, rr = rel - qt * 5;
        int wid = nl * 4 + qt;
        int base = fbb[fb] + swo[fb * 64 + wid];
        int b0 = node * 20 + qt * 5;
        for (int r = 0; r < rr; ++r) base += blen[b0 + r];
        binpos[i] = base;
    }
    __syncthreads();
    // scatter in schedule order with rowoff payload
    for (int i = beg + t; i < end; i += 512) {
        unsigned v = tmp[i];
        int dl = (int)(v >> 22), rel = (int)(v & 31u);
        int ro = rel * (16 * PADR) + (dl & 15) * PADR;
        int key = dl * NUM_RELS + rel;
        int pos = atomicAdd(&binpos[key], 1);
        edgedata[pos] = ((v >> 5) & 0x1FFFFu) | ((unsigned)ro << 17);
    }
}

// ---------------- dtype conversions ----------------

__global__ void f2b_kernel(const float* __restrict__ in, unsigned short* __restrict__ out,
                           int n4) {
    int i = blockIdx.x * 256 + threadIdx.x;
    if (i >= n4) return;
    float4 v = ((const float4*)in)[i];
    ushort4 o;
    o.x = f2bf(v.x); o.y = f2bf(v.y); o.z = f2bf(v.z); o.w = f2bf(v.w);
    ((ushort4*)out)[i] = o;
}

// W[r][d][o] fp32 -> Wb[r][o][d] bf16 (B-frag layout, verified round 4)
__global__ void wconv_kernel(const float* __restrict__ W, unsigned short* __restrict__ Wb) {
    int r = blockIdx.x;
    for (int i = threadIdx.x; i < D * D; i += 256) {
        int d2 = i >> 6, o = i & 63;
        Wb[(size_t)r * (D * D) + o * D + d2] = f2bf(W[(size_t)r * (D * D) + d2 * D + o]);
    }
}

// ---------------- fused layer ----------------
// Block = 16 dst nodes (= one fb), 8 waves. Group gidx = wave*4+grp in [0,32)
// processes the contiguous balanced span [sched_off[fb*32+gidx],
// sched_off[fb*32+gidx+1]) of schedule-ordered edges. Each edge word carries
// its A-row offset ro = w>>17 directly; run-reset key is ro itself (covers
// node and rel-quarter boundaries automatically; runs never straddle spans).
// Double-buffered 8-edge batches (issue batch g+2 words + g+1 rows, process
// g); tail merged via clamp-to-endm1 + x=0 masking (rewrites same bf16 ->
// bit-identical). Waves 0-3 then do the 40-MFMA transform (verified layouts).
// mode 1: relu'd bf16; mode 2: fp32.
__global__ __launch_bounds__(512, 6) void fused_layer(
    const unsigned short* __restrict__ xb, const unsigned short* __restrict__ Wb,
    const unsigned* __restrict__ edgedata, const int* __restrict__ sched_off,
    unsigned short* __restrict__ xbout, float* __restrict__ h2out, int mode) {
    __shared__ __align__(16) unsigned short A[NUM_RELS * 16 * PADR];  // 46080 B
    int wave = threadIdx.x >> 6, lane = threadIdx.x & 63;
    int grp = lane >> 4, l4 = lane & 15;
    int gidx = wave * 4 + grp;         // 0..31
    int colb = l4 * 4;                 // column base, 0..60

    for (int i = threadIdx.x; i < NUM_RELS * 16 * PADR / 8; i += 512)
        ((int4*)A)[i] = (int4){0, 0, 0, 0};
    __syncthreads();

    int beg = sched_off[blockIdx.x * 32 + gidx];
    int end = sched_off[blockIdx.x * 32 + gidx + 1];
    int cnt = end - beg;
    int nb = (cnt + 7) >> 3;           // number of (padded) batches
    int nbmax = max(nb, __shfl_xor(nb, 16));
    nbmax = max(nbmax, __shfl_xor(nbmax, 32));
    int endm1 = end - 1;

    float a0 = 0.f, a1 = 0.f, a2 = 0.f, a3 = 0.f;
    unsigned roprev = 0xFFFFFFFFu;
    unsigned short* Ac = A + (unsigned)colb;

    auto rowload = [&](unsigned ewv) -> uint2 {
        return *(const uint2*)(xb + ((ewv & 0x1FFFFu) << 6) + (unsigned)colb);
    };
    auto proc = [&](unsigned (&ewc)[8], uint2 (&xv)[8], int valid) {
#pragma unroll
        for (int j = 0; j < 8; ++j) {
            unsigned ro = ewc[j] >> 17;
            bool real = j < valid;
            unsigned mx = real ? xv[j].x : 0u;
            unsigned my = real ? xv[j].y : 0u;
            bool keep = (ro == roprev);
            a0 = (keep ? a0 : 0.f) + bf2f_lo(mx);
            a1 = (keep ? a1 : 0.f) + bf2f_hi(mx);
            a2 = (keep ? a2 : 0.f) + bf2f_lo(my);
            a3 = (keep ? a3 : 0.f) + bf2f_hi(my);
            uint2 o;
            o.x = cvt_pk_bf16(a0, a1);
            o.y = cvt_pk_bf16(a2, a3);
            *(uint2*)(Ac + ro) = o;
            roprev = ro;
        }
    };

    unsigned ewA[8], ewB[8];
    uint2 xvA[8], xvB[8];
    if (nb > 0) {
#pragma unroll
        for (int j = 0; j < 8; ++j) ewA[j] = edgedata[min(beg + j, endm1)];
    }
    if (nb > 1) {
#pragma unroll
        for (int j = 0; j < 8; ++j) ewB[j] = edgedata[min(beg + 8 + j, endm1)];
    }
    if (nb > 0) {
#pragma unroll
        for (int j = 0; j < 8; ++j) xvA[j] = rowload(ewA[j]);
    }

    for (int g = 0; g < nbmax;) {
        {   // even phase: current = A buffers, next = B
            bool act = g < nb;
            if (act) {
                unsigned ewc[8];
#pragma unroll
                for (int j = 0; j < 8; ++j) ewc[j] = ewA[j];
                int nbase = beg + (g + 2) * 8;
                if (g + 2 < nb) {
#pragma unroll
                    for (int j = 0; j < 8; ++j)
                        ewA[j] = edgedata[min(nbase + j, endm1)];
                }
                if (g + 1 < nb) {
#pragma unroll
                    for (int j = 0; j < 8; ++j) xvB[j] = rowload(ewB[j]);
                }
                proc(ewc, xvA, cnt - g * 8);
            }
        }
        ++g;
        if (g >= nbmax) break;
        {   // odd phase: current = B buffers, next = A
            bool act = g < nb;
            if (act) {
                unsigned ewc[8];
#pragma unroll
                for (int j = 0; j < 8; ++j) ewc[j] = ewB[j];
                int nbase = beg + (g + 2) * 8;
                if (g + 2 < nb) {
#pragma unroll
                    for (int j = 0; j < 8; ++j)
                        ewB[j] = edgedata[min(nbase + j, endm1)];
                }
                if (g + 1 < nb) {
#pragma unroll
                    for (int j = 0; j < 8; ++j) xvA[j] = rowload(ewA[j]);
                }
                proc(ewc, xvB, cnt - g * 8);
            }
        }
        ++g;
    }
    __syncthreads();

    // waves 0-3: transform. wave w covers output columns w*16..w*16+15
    if (wave < 4) {
        int lrow = lane & 15, lhi = lane >> 4;
        f32x4 C = {0.f, 0.f, 0.f, 0.f};
        for (int q = 0; q < NUM_RELS; ++q) {
            const unsigned short* Arow = &A[(q * 16 + lrow) * PADR + lhi * 8];
            bf16x8 aa0 = *(const bf16x8*)(Arow);        // k = lhi*8 + j
            bf16x8 aa1 = *(const bf16x8*)(Arow + 32);   // k = 32 + lhi*8 + j
            const unsigned short* wrow = Wb + ((size_t)q << 12)
                                         + (size_t)(wave * 16 + lrow) * D + lhi * 8;
            bf16x8 b0 = *(const bf16x8*)(wrow);
            bf16x8 b1 = *(const bf16x8*)(wrow + 32);
            C = __builtin_amdgcn_mfma_f32_16x16x32_bf16(aa0, b0, C, 0, 0, 0);
            C = __builtin_amdgcn_mfma_f32_16x16x32_bf16(aa1, b1, C, 0, 0, 0);
        }
        // C/D: row = lhi*4 + reg (dst-local), col = wave*16 + lrow
#pragma unroll
        for (int reg = 0; reg < 4; ++reg) {
            int onode = blockIdx.x * 16 + lhi * 4 + reg;
            int col = wave * 16 + lrow;
            if (mode == 1)
                xbout[(size_t)onode * D + col] = f2bf(fmaxf(C[reg], 0.f));
            else
                h2out[(size_t)onode * D + col] = C[reg];
        }
    }
}

// ---------------- readout ----------------

__global__ void colsum_kernel(const float* __restrict__ h2,
                              float* __restrict__ g, int n) {
    __shared__ float s[256];
    int tid = threadIdx.x;
    int col = tid & 63;
    int rowgrp = (blockIdx.x * blockDim.x + tid) >> 6;
    int nrowgrp = (gridDim.x * blockDim.x) >> 6;
    float acc = 0.0f;
    for (int row = rowgrp; row < n; row += nrowgrp)
        acc += h2[(size_t)row * D + col];
    s[tid] = acc;
    __syncthreads();
    if (tid < 64) {
        acc = s[tid] + s[tid + 64] + s[tid + 128] + s[tid + 192];
        atomicAdd(&g[col], acc);
    }
}

__global__ void mlp_kernel(const float* __restrict__ g,
                           const float* __restrict__ A1w,
                           const float* __restrict__ A1b,
                           const float* __restrict__ A2w,
                           const float* __restrict__ A2b,
                           float* __restrict__ out, float invN) {
    __shared__ float a1[HID_ATTR];
    int t = threadIdx.x;
    if (t < HID_ATTR) {
        float acc = A1b[t];
#pragma unroll
        for (int d2 = 0; d2 < D; ++d2)
            acc = fmaf(g[d2] * invN, A1w[d2 * HID_ATTR + t], acc);
        a1[t] = fmaxf(acc, 0.0f);
    }
    __syncthreads();
    if (t < OUT_ATTR) {
        float acc = A2b[t];
#pragma unroll
        for (int j = 0; j < HID_ATTR; ++j)
            acc = fmaf(a1[j], A2w[j * OUT_ATTR + t], acc);
        out[t] = 1.0f / (1.0f + expf(-acc));
    }
}

// ---------------- launch ----------------

extern "C" void kernel_launch(void* const* d_in, const int* in_sizes, int n_in,
                              void* d_out, int out_size, void* d_ws, size_t ws_size,
                              hipStream_t stream) {
    const float* h   = (const float*)d_in[0];
    const int* src   = (const int*)d_in[1];
    const int* dst   = (const int*)d_in[2];
    const int* etype = (const int*)d_in[3];
    const float* W1  = (const float*)d_in[4];
    const float* W2  = (const float*)d_in[5];
    const float* A1w = (const float*)d_in[6];
    const float* A1b = (const float*)d_in[7];
    const float* A2w = (const float*)d_in[8];
    const float* A2b = (const float*)d_in[9];

    float* out_h2 = (float*)d_out;
    float* out_a  = out_h2 + (size_t)N_NODES * D;

    // workspace layout (int offsets from d_ws; all buffers 16B-aligned)
    int* base       = (int*)d_ws;
    float* gsum     = (float*)base;               // 64 f32
    int* hist_b     = base + 64;                  // 448 (NB padded)
    int* bbase      = base + 512;                 // 448 (NB+1)
    int* bcur       = base + 960;                 // 448
    int* sched_off  = base + 1408;                // 200,064 (NFB*32 + 1 padded)
    unsigned* tmp   = (unsigned*)(base + 201472); // 3,200,000
    unsigned* edgedata = (unsigned*)(base + 3401472); // 3,200,000
    unsigned short* xb  = (unsigned short*)(base + 6601472);   // 6.4M u16
    unsigned short* xb2 = (unsigned short*)(base + 9801472);   // 6.4M u16
    unsigned short* w1b = (unsigned short*)(base + 13001472);  // 81,920 u16
    unsigned short* w2b = (unsigned short*)(base + 13042432);  // 81,920 u16
    // total: 13,083,392 ints = 52.3 MB

    hipMemsetAsync(hist_b, 0, NB * sizeof(int), stream);
    hipMemsetAsync(gsum, 0, 64 * sizeof(float), stream);

    // CSR sorted by (dst, rel) with balanced per-block schedule
    hist_bucket_kernel<<<PA_GRID, PA_THREADS, 0, stream>>>(dst, hist_b);
    scan_bucket_kernel<<<1, 512, 0, stream>>>(hist_b, bbase, bcur, sched_off);
    passA_kernel<<<PA_GRID, PA_THREADS, 0, stream>>>(src, dst, etype, bcur, tmp);
    passB_kernel<<<NB, 512, 0, stream>>>(tmp, bbase, edgedata, sched_off);

    // conversions
    wconv_kernel<<<NUM_RELS, 256, 0, stream>>>(W1, w1b);
    wconv_kernel<<<NUM_RELS, 256, 0, stream>>>(W2, w2b);
    f2b_kernel<<<(N_NODES * D / 4 + 255) / 256, 256, 0, stream>>>(h, xb, N_NODES * D / 4);

    // two fused RGCN layers
    fused_layer<<<NFB, 512, 0, stream>>>(xb, w1b, edgedata, sched_off,
                                         xb2, nullptr, 1);
    fused_layer<<<NFB, 512, 0, stream>>>(xb2, w2b, edgedata, sched_off,
                                         nullptr, out_h2, 2);

    // readout
    colsum_kernel<<<512, 256, 0, stream>>>(out_h2, gsum, N_NODES);
    mlp_kernel<<<1, 64, 0, stream>>>(gsum, A1w, A1b, A2w, A2b,
                                     out_a, 1.0f / (float)N_NODES);
}